// Round 2
// baseline (3478.572 us; speedup 1.0000x reference)
//
#include <hip/hip_runtime.h>
#include <hip/hip_bf16.h>

#define NZv 1
#define NYv 400
#define NXv 352
#define Bv 4
#define CANVASv (Bv * NZv * NYv * NXv) /* 563200 */
#define EPSF 0.001f
#define VXF 0.2f
#define VYF 0.2f
#define VZF 4.0f
#define XOFFv 0.1f
#define YOFFv -39.9f
#define ZOFFv -1.0f
#define MB1 1024  /* moment1 grid */

typedef __attribute__((ext_vector_type(8))) short bf16x8;
typedef __attribute__((ext_vector_type(4))) float f32x4;

__device__ __forceinline__ short f2bf(float f) {
    union { __hip_bfloat16 h; short s; } u;
    u.h = __float2bfloat16(f);
    return u.s;
}
__device__ __forceinline__ float bf2f(short s) {
    return __uint_as_float(((unsigned int)(unsigned short)s) << 16);
}
__device__ __forceinline__ unsigned int pk(float a, float b) {
    return (unsigned int)(unsigned short)f2bf(a) | ((unsigned int)(unsigned short)f2bf(b) << 16);
}

// ---------------- scatter pass 1: count + coord sums ----------------
__global__ void k_scatter1(const float4* __restrict__ feat, const int4* __restrict__ coors,
                           int* __restrict__ vidx, float* __restrict__ counts,
                           float* __restrict__ sumc, int n)
{
    int i = blockIdx.x * blockDim.x + threadIdx.x;
    if (i >= n) return;
    int4 c = coors[i];
    int v = ((c.x * NZv + c.y) * NYv + c.z) * NXv + c.w;
    vidx[i] = v;
    float4 f = feat[i];
    atomicAdd(&counts[v], 1.0f);
    atomicAdd(&sumc[3 * v + 0], f.x);
    atomicAdd(&sumc[3 * v + 1], f.y);
    atomicAdd(&sumc[3 * v + 2], f.z);
}

// ---------------- scatter pass 2: mean-dist sums ----------------
__global__ void k_scatter2(const float4* __restrict__ feat, const int* __restrict__ vidx,
                           const float* __restrict__ counts, const float* __restrict__ sumc,
                           float* __restrict__ spd, int n)
{
    int i = blockIdx.x * blockDim.x + threadIdx.x;
    if (i >= n) return;
    int v = vidx[i];
    float safe = fmaxf(counts[v], 1.0f);
    float inv = 1.0f / safe;
    float4 f = feat[i];
    float dx = f.x - sumc[3 * v + 0] * inv;
    float dy = f.y - sumc[3 * v + 1] * inv;
    float dz = f.z - sumc[3 * v + 2] * inv;
    atomicAdd(&spd[v], sqrtf(dx * dx + dy * dy + dz * dz));
}

// ---------------- prex: build x bf16[n][16] + 14x14 moment accumulation ----------------
__global__ __launch_bounds__(256, 2) void k_prex(const float4* __restrict__ feat,
                       const int4* __restrict__ coors,
                       const int* __restrict__ vidx, const float* __restrict__ counts,
                       const float* __restrict__ sumc, const float* __restrict__ spd,
                       unsigned int* __restrict__ x, double* __restrict__ md0, int n)
{
    float mv[105];
#pragma unroll
    for (int e = 0; e < 105; ++e) mv[e] = 0.f;
    int t = threadIdx.x;
    int stride = gridDim.x * blockDim.x;
    for (int i = blockIdx.x * blockDim.x + t; i < n; i += stride) {
        float4 f = feat[i];
        int4 c = coors[i];
        int v = vidx[i];
        float safe = fmaxf(counts[v], 1.0f);
        float inv = 1.0f / safe;
        float vals[14];
        vals[0] = f.x; vals[1] = f.y; vals[2] = f.z; vals[3] = f.w;
        vals[4] = safe / 0.16f;
        vals[5] = spd[v] * inv;
        vals[6] = f.x - sumc[3 * v + 0] * inv;
        vals[7] = f.y - sumc[3 * v + 1] * inv;
        vals[8] = f.z - sumc[3 * v + 2] * inv;
        vals[9]  = f.x - ((float)c.w * VXF + XOFFv);
        vals[10] = f.y - ((float)c.z * VYF + YOFFv);
        vals[11] = f.z - ((float)c.y * VZF + ZOFFv);
        vals[12] = sqrtf(f.x * f.x + f.y * f.y + f.z * f.z);
        vals[13] = 1.0f;
        // moments
        int idx = 0;
#pragma unroll
        for (int a = 0; a < 14; ++a)
#pragma unroll
            for (int b = a; b < 14; ++b) { mv[idx] = fmaf(vals[a], vals[b], mv[idx]); ++idx; }
        // write x row (16 bf16 = 8 u32)
        unsigned int row[8];
#pragma unroll
        for (int q = 0; q < 6; ++q) row[q] = pk(vals[2 * q], vals[2 * q + 1]);
        row[6] = pk(vals[12], 0.f);
        row[7] = 0u;
        uint4* dst = (uint4*)(x + (size_t)i * 8);
        dst[0] = make_uint4(row[0], row[1], row[2], row[3]);
        dst[1] = make_uint4(row[4], row[5], row[6], row[7]);
    }
    // reduce moments: wave shuffle -> LDS -> double atomics
    __shared__ float wacc[4][105];
    int lane = t & 63, wid = t >> 6;
#pragma unroll
    for (int e = 0; e < 105; ++e) {
        float v = mv[e];
        for (int m = 1; m < 64; m <<= 1) v += __shfl_xor(v, m);
        if (lane == 0) wacc[wid][e] = v;
    }
    __syncthreads();
    if (t < 105) {
        double s = (double)wacc[0][t] + (double)wacc[1][t] + (double)wacc[2][t] + (double)wacc[3][t];
        atomicAdd(&md0[t], s);
    }
}

__device__ __forceinline__ int idx14(int a, int b) { // a<=b
    return a * 14 - a * (a - 1) / 2 + (b - a);
}

// ---------------- fin0: BN0 scale/shift from moments ----------------
__global__ void k_fin0(const double* __restrict__ md0, const float* __restrict__ W0,
                       const float* __restrict__ g0, const float* __restrict__ b0,
                       float* __restrict__ sc0, float* __restrict__ sh0, int n)
{
    __shared__ double mom[105];
    int t = threadIdx.x;
    for (int e = t; e < 105; e += 64) mom[e] = md0[e];
    __syncthreads();
    double nn = (double)n;
    double mu[13];
#pragma unroll
    for (int j = 0; j < 13; ++j) mu[j] = mom[idx14(j, 13)] / nn;
    double wc[13];
#pragma unroll
    for (int j = 0; j < 13; ++j) wc[j] = (double)W0[j * 64 + t];
    double meanc = 0.0, var = 0.0;
#pragma unroll
    for (int j = 0; j < 13; ++j) {
        meanc += mu[j] * wc[j];
        for (int k = 0; k < 13; ++k) {
            int a = j < k ? j : k, b = j < k ? k : j;
            double cov = mom[idx14(a, b)] / nn - mu[j] * mu[k];
            var += cov * wc[j] * wc[k];
        }
    }
    float scale = g0[t] * rsqrtf((float)var + EPSF);
    sc0[t] = scale;
    sh0[t] = b0[t] - (float)meanc * scale;
}

// ---------------- gemm0: x(13) @ W0 -> BN+ReLU -> p0 bf16 + vmax atomicMax ----------------
__global__ __launch_bounds__(256) void k_gemm0(const unsigned int* __restrict__ x,
    const float* __restrict__ W0, const int* __restrict__ vidx,
    const float* __restrict__ sc0, const float* __restrict__ sh0,
    unsigned int* __restrict__ p0, unsigned int* __restrict__ vmax, int n)
{
    __shared__ float sW[13][64];
    __shared__ float ssc[64], ssh[64];
    int t = threadIdx.x;
    for (int e = t; e < 13 * 64; e += 256) sW[e >> 6][e & 63] = W0[e];
    if (t < 64) { ssc[t] = sc0[t]; ssh[t] = sh0[t]; }
    __syncthreads();
    int gid = blockIdx.x * 256 + t;
    int i = gid >> 1, half = gid & 1;
    if (i >= n) return;
    const uint4* xr = (const uint4*)(x + (size_t)i * 8);
    uint4 r0 = xr[0], r1 = xr[1];
    unsigned int rw[8] = {r0.x, r0.y, r0.z, r0.w, r1.x, r1.y, r1.z, r1.w};
    float vals[13];
#pragma unroll
    for (int k = 0; k < 13; ++k) {
        unsigned int u = rw[k >> 1];
        vals[k] = bf2f((short)((k & 1) ? (u >> 16) : (u & 0xFFFF)));
    }
    float acc[32];
#pragma unroll
    for (int c = 0; c < 32; ++c) acc[c] = 0.f;
#pragma unroll
    for (int k = 0; k < 13; ++k) {
        float xk = vals[k];
#pragma unroll
        for (int c = 0; c < 32; ++c) acc[c] = fmaf(xk, sW[k][half * 32 + c], acc[c]);
    }
    int v = vidx[i];
    unsigned int outw[16];
    float pv[32];
#pragma unroll
    for (int c = 0; c < 32; ++c) {
        int ch = half * 32 + c;
        pv[c] = fmaxf(fmaf(acc[c], ssc[ch], ssh[ch]), 0.f);
    }
#pragma unroll
    for (int q = 0; q < 16; ++q) outw[q] = pk(pv[2 * q], pv[2 * q + 1]);
    uint4* dst = (uint4*)(p0 + (size_t)i * 32 + half * 16);
#pragma unroll
    for (int q = 0; q < 4; ++q) dst[q] = make_uint4(outw[4 * q], outw[4 * q + 1], outw[4 * q + 2], outw[4 * q + 3]);
    unsigned int* vrow = vmax + (size_t)v * 64 + half * 32;
#pragma unroll
    for (int c = 0; c < 32; ++c) atomicMax(&vrow[c], __float_as_uint(pv[c]));
}

// ---------------- moment1: M1 = X1^T X1 via MFMA (X1 = [p0 | vmax[vidx]]) ----------------
__global__ __launch_bounds__(256) void k_moment1(const unsigned int* __restrict__ p0,
    const float* __restrict__ vmaxf, const int* __restrict__ vidx,
    float* __restrict__ partials, float* __restrict__ s1, int n, int nchunks)
{
    __shared__ __align__(16) char xt[128 * 128];
    int t = threadIdx.x, lane = t & 63, wid = t >> 6;
    int p = t >> 3, s = t & 7;
    int k0 = (s < 4) ? s * 16 : 64 + (s - 4) * 16;
    float psum[16];
#pragma unroll
    for (int j = 0; j < 16; ++j) psum[j] = 0.f;
    f32x4 acc[2][8];
#pragma unroll
    for (int a = 0; a < 2; ++a)
#pragma unroll
        for (int b = 0; b < 8; ++b) acc[a][b] = (f32x4){0.f, 0.f, 0.f, 0.f};

    for (int c = blockIdx.x; c < nchunks; c += gridDim.x) {
        int base = c * 32;
        int i = base + p;
        bool valid = i < n;
        short vals16[16];
        if (valid) {
            if (s < 4) {
                const uint4* src = (const uint4*)(p0 + (size_t)i * 32 + s * 8);
                uint4 d0 = src[0], d1 = src[1];
                unsigned int w[8] = {d0.x, d0.y, d0.z, d0.w, d1.x, d1.y, d1.z, d1.w};
#pragma unroll
                for (int j = 0; j < 8; ++j) {
                    vals16[2 * j] = (short)(w[j] & 0xFFFF);
                    vals16[2 * j + 1] = (short)(w[j] >> 16);
                }
            } else {
                const float4* src = (const float4*)(vmaxf + (size_t)vidx[i] * 64 + (s - 4) * 16);
                float4 f0 = src[0], f1 = src[1], f2 = src[2], f3 = src[3];
                float fv[16] = {f0.x, f0.y, f0.z, f0.w, f1.x, f1.y, f1.z, f1.w,
                                f2.x, f2.y, f2.z, f2.w, f3.x, f3.y, f3.z, f3.w};
#pragma unroll
                for (int j = 0; j < 16; ++j) vals16[j] = f2bf(fv[j]);
            }
        } else {
#pragma unroll
            for (int j = 0; j < 16; ++j) vals16[j] = 0;
        }
        __syncthreads();
#pragma unroll
        for (int j = 0; j < 16; ++j) {
            int k = k0 + j;
            *(short*)(xt + k * 128 + ((p * 2) ^ ((k & 7) << 4))) = vals16[j];
            psum[j] += bf2f(vals16[j]);
        }
        __syncthreads();
        int rsel = lane & 15, ko2 = (lane >> 4) * 16;
        bf16x8 a0 = *(bf16x8*)(xt + (32 * wid + rsel) * 128 + (ko2 ^ ((rsel & 7) << 4)));
        bf16x8 a1 = *(bf16x8*)(xt + (32 * wid + 16 + rsel) * 128 + (ko2 ^ ((rsel & 7) << 4)));
#pragma unroll
        for (int cf = 0; cf < 8; ++cf) {
            int cc = cf * 16 + rsel;
            bf16x8 b = *(bf16x8*)(xt + cc * 128 + (ko2 ^ ((cc & 7) << 4)));
            acc[0][cf] = __builtin_amdgcn_mfma_f32_16x16x32_bf16(a0, b, acc[0][cf], 0, 0, 0);
            acc[1][cf] = __builtin_amdgcn_mfma_f32_16x16x32_bf16(a1, b, acc[1][cf], 0, 0, 0);
        }
    }
    // write partials
    size_t pb = (size_t)blockIdx.x * 16384;
#pragma unroll
    for (int rf = 0; rf < 2; ++rf)
#pragma unroll
        for (int cf = 0; cf < 8; ++cf)
#pragma unroll
            for (int jj = 0; jj < 4; ++jj) {
                int row = 32 * wid + rf * 16 + (lane >> 4) * 4 + jj;
                int col = cf * 16 + (lane & 15);
                partials[pb + row * 128 + col] = acc[rf][cf][jj];
            }
    // s1 reduction (sum over p-groups within wave)
#pragma unroll
    for (int j = 0; j < 16; ++j) {
        float v = psum[j];
        v += __shfl_xor(v, 8);
        v += __shfl_xor(v, 16);
        v += __shfl_xor(v, 32);
        if ((lane >> 3) == 0) {
            int ss = lane & 7;
            int kk = ((ss < 4) ? ss * 16 : 64 + (ss - 4) * 16) + j;
            atomicAdd(&s1[kk], v);
        }
    }
}

// ---------------- reduce M1 partials ----------------
__global__ void k_redM1(const float* __restrict__ partials, float* __restrict__ M1)
{
    int e = blockIdx.x * 256 + threadIdx.x;
    float s = 0.f;
#pragma unroll 8
    for (int r = 0; r < MB1; ++r) s += partials[(size_t)r * 16384 + e];
    M1[e] = s;
}

// ---------------- fin1: BN1 scale/shift via quadratic form ----------------
__global__ __launch_bounds__(256) void k_fin1(const float* __restrict__ M1, const float* __restrict__ s1,
    const float* __restrict__ W1, const float* __restrict__ g1, const float* __restrict__ b1,
    float* __restrict__ sc1, float* __restrict__ sh1, int n)
{
    __shared__ float mu[128];
    int t = threadIdx.x, lane = t & 63, wv = t >> 6;
    float invn = 1.f / (float)n;
    if (t < 128) mu[t] = s1[t] * invn;
    __syncthreads();
    int c = blockIdx.x * 4 + wv;
    float q = 0.f;
    for (int it = 0; it < 256; ++it) {
        int e = it * 64 + lane;
        int j = e >> 7, k = e & 127;
        float cv = M1[e] * invn - mu[j] * mu[k];
        q = fmaf(cv * W1[j * 128 + c], W1[k * 128 + c], q);
    }
    float m = fmaf(mu[lane], W1[lane * 128 + c], mu[lane + 64] * W1[(lane + 64) * 128 + c]);
    for (int msk = 1; msk < 64; msk <<= 1) { q += __shfl_xor(q, msk); m += __shfl_xor(m, msk); }
    if (lane == 0) {
        float scale = g1[c] * rsqrtf(q + EPSF);
        sc1[c] = scale;
        sh1[c] = b1[c] - m * scale;
    }
}

// ---------------- fused: x1 @ W1 -> BN+ReLU -> [.|fsp] @ Ws + bs -> ReLU -> out ----------------
#define SW1_OFF 0
#define SWS_OFF 32768
#define SX_OFF  (32768 + 49152)
#define SCL_OFF (32768 + 49152 + 49152)
#define FUSED_LDS (SCL_OFF + 1536)

__global__ __launch_bounds__(512, 2) void k_fused(const unsigned int* __restrict__ p0,
    const float* __restrict__ vmaxf, const int* __restrict__ vidx,
    const unsigned int* __restrict__ xrows,
    const float* __restrict__ W1, const float* __restrict__ Wsp, const float* __restrict__ bsp,
    const float* __restrict__ sc1, const float* __restrict__ sh1,
    float* __restrict__ out, int n, int ntiles)
{
    extern __shared__ char lds[];
    char* sW1 = lds + SW1_OFF;
    char* sWs = lds + SWS_OFF;
    char* sx  = lds + SX_OFF;
    float* ssc = (float*)(lds + SCL_OFF);
    float* ssh = ssc + 128;
    float* sbs = ssh + 128;
    int t = threadIdx.x, lane = t & 63, w = t >> 6;

    // stage W1 (128x128) -> sW1[c][k] bf16 swizzled, stride 256
#pragma unroll
    for (int it = 0; it < 8; ++it) {
        int e = (it * 512 + t) * 4;
        float4 wv = *(const float4*)(W1 + e);
        int k = e >> 7, c0 = e & 127;
        float wa[4] = {wv.x, wv.y, wv.z, wv.w};
#pragma unroll
        for (int q = 0; q < 4; ++q) {
            int c = c0 + q;
            *(short*)(sW1 + c * 256 + ((k * 2) ^ ((c & 7) << 4))) = f2bf(wa[q]);
        }
    }
    // stage Ws (130x128) -> sWs[c][k] bf16 swizzled, stride 384
    for (int it = 0; it < 9; ++it) {
        int e = (it * 512 + t) * 4;
        if (e < 16640) {
            float4 wv = *(const float4*)(Wsp + e);
            int k = e >> 7, c0 = e & 127;
            float wa[4] = {wv.x, wv.y, wv.z, wv.w};
#pragma unroll
            for (int q = 0; q < 4; ++q) {
                int c = c0 + q;
                *(short*)(sWs + c * 384 + ((k * 2) ^ ((c & 7) << 4))) = f2bf(wa[q]);
            }
        }
    }
    // zero pad cols k in [130,160) for sWs and sx  (byte k2 in [260,320))
    for (int e = t; e < 1920; e += 512) {
        int r = e / 15, q = e - r * 15;
        int k2 = 260 + 4 * q;
        *(unsigned int*)(sWs + r * 384 + (k2 ^ ((r & 7) << 4))) = 0u;
        *(unsigned int*)(sx  + r * 384 + (k2 ^ ((r & 7) << 4))) = 0u;
    }
    if (t < 128) { ssc[t] = sc1[t]; ssh[t] = sh1[t]; sbs[t] = bsp[t]; }
    __syncthreads();

    int rA = w * 16 + (lane & 15);
    unsigned int szA = (rA & 7) << 4;

    for (int tile = blockIdx.x; tile < ntiles; tile += gridDim.x) {
        int base = tile * 128;
        // ---- stage x1 tile: rows 0..127, cols 0..127 bf16 ----
        {
            int p = t >> 2, s = t & 3;
            int i = base + p; if (i >= n) i = n - 1;
            char* rowp = sx + p * 384;
            unsigned int sz = (p & 7) << 4;
            if (s < 2) {
                const uint4* src = (const uint4*)(p0 + (size_t)i * 32 + s * 16);
                uint4 d0 = src[0], d1 = src[1], d2 = src[2], d3 = src[3];
                int k2 = s * 64;
                *(uint4*)(rowp + ((k2 +  0) ^ sz)) = d0;
                *(uint4*)(rowp + ((k2 + 16) ^ sz)) = d1;
                *(uint4*)(rowp + ((k2 + 32) ^ sz)) = d2;
                *(uint4*)(rowp + ((k2 + 48) ^ sz)) = d3;
            } else {
                const float4* src = (const float4*)(vmaxf + (size_t)vidx[i] * 64 + (s - 2) * 32);
                float4 f[8];
#pragma unroll
                for (int q = 0; q < 8; ++q) f[q] = src[q];
                unsigned int ww[16];
#pragma unroll
                for (int q = 0; q < 8; ++q) {
                    ww[2 * q]     = pk(f[q].x, f[q].y);
                    ww[2 * q + 1] = pk(f[q].z, f[q].w);
                }
                int k2 = 128 + (s - 2) * 64;
#pragma unroll
                for (int q = 0; q < 4; ++q)
                    *(uint4*)(rowp + ((k2 + 16 * q) ^ sz)) =
                        make_uint4(ww[4 * q], ww[4 * q + 1], ww[4 * q + 2], ww[4 * q + 3]);
            }
        }
        __syncthreads();
        // ---- MFMA stage 1: y1 = x1 @ W1 ----
        f32x4 acc1[8];
#pragma unroll
        for (int cf = 0; cf < 8; ++cf) acc1[cf] = (f32x4){0.f, 0.f, 0.f, 0.f};
#pragma unroll
        for (int kc = 0; kc < 4; ++kc) {
            int ko2 = kc * 64 + (lane >> 4) * 16;
            bf16x8 a = *(bf16x8*)(sx + rA * 384 + (ko2 ^ szA));
#pragma unroll
            for (int cf = 0; cf < 8; ++cf) {
                int rb = cf * 16 + (lane & 15);
                bf16x8 b = *(bf16x8*)(sW1 + rb * 256 + (ko2 ^ ((rb & 7) << 4)));
                acc1[cf] = __builtin_amdgcn_mfma_f32_16x16x32_bf16(a, b, acc1[cf], 0, 0, 0);
            }
        }
        __syncthreads();
        // ---- BN+ReLU -> x2 (cols 0..127) + fsp (cols 128,129) ----
#pragma unroll
        for (int cf = 0; cf < 8; ++cf) {
            int c = cf * 16 + (lane & 15);
            float sc = ssc[c], sh = ssh[c];
#pragma unroll
            for (int j = 0; j < 4; ++j) {
                int r = w * 16 + (lane >> 4) * 4 + j;
                float pvv = fmaxf(fmaf(acc1[cf][j], sc, sh), 0.f);
                *(short*)(sx + r * 384 + ((c * 2) ^ ((r & 7) << 4))) = f2bf(pvv);
            }
        }
        if (t < 128) {
            int i = base + t; if (i >= n) i = n - 1;
            unsigned int fs = *(const unsigned int*)((const char*)xrows + (size_t)i * 32 + 8);
            *(unsigned int*)(sx + t * 384 + (256 ^ ((t & 7) << 4))) = fs;
        }
        __syncthreads();
        // ---- MFMA stage 2: out = relu(x2 @ Ws + bs) ----
        f32x4 acc2[8];
#pragma unroll
        for (int cf = 0; cf < 8; ++cf) acc2[cf] = (f32x4){0.f, 0.f, 0.f, 0.f};
#pragma unroll
        for (int kc = 0; kc < 5; ++kc) {
            int ko2 = kc * 64 + (lane >> 4) * 16;
            bf16x8 a = *(bf16x8*)(sx + rA * 384 + (ko2 ^ szA));
#pragma unroll
            for (int cf = 0; cf < 8; ++cf) {
                int rb = cf * 16 + (lane & 15);
                bf16x8 b = *(bf16x8*)(sWs + rb * 384 + (ko2 ^ ((rb & 7) << 4)));
                acc2[cf] = __builtin_amdgcn_mfma_f32_16x16x32_bf16(a, b, acc2[cf], 0, 0, 0);
            }
        }
#pragma unroll
        for (int cf = 0; cf < 8; ++cf) {
            int c = cf * 16 + (lane & 15);
            float bsv = sbs[c];
#pragma unroll
            for (int j = 0; j < 4; ++j) {
                int r = w * 16 + (lane >> 4) * 4 + j;
                int i = base + r;
                if (i < n) out[(size_t)i * 128 + c] = fmaxf(acc2[cf][j] + bsv, 0.f);
            }
        }
        __syncthreads();
    }
}

extern "C" void kernel_launch(void* const* d_in, const int* in_sizes, int n_in,
                              void* d_out, int out_size, void* d_ws, size_t ws_size,
                              hipStream_t stream)
{
    const float* feat = (const float*)d_in[0];
    const int*   coor = (const int*)d_in[1];
    const float* W0   = (const float*)d_in[2];
    const float* g0   = (const float*)d_in[3];
    const float* b0   = (const float*)d_in[4];
    const float* W1   = (const float*)d_in[5];
    const float* g1   = (const float*)d_in[6];
    const float* b1   = (const float*)d_in[7];
    const float* Wsp  = (const float*)d_in[8];
    const float* bsp  = (const float*)d_in[9];
    float* outp = (float*)d_out;

    int n = in_sizes[0] / 4;
    size_t npad = ((size_t)n + 127) & ~127ULL;

    char* ws = (char*)d_ws;
    size_t off = 0;
    auto alloc = [&](size_t bytes) { char* p = ws + off; off = (off + bytes + 255) & ~255ULL; return p; };
    int*          vidx   = (int*)alloc(npad * 4);
    float*        counts = (float*)alloc((size_t)CANVASv * 4);
    float*        sumc   = (float*)alloc((size_t)CANVASv * 12);
    float*        spd    = (float*)alloc((size_t)CANVASv * 4);
    unsigned int* x      = (unsigned int*)alloc(npad * 32);
    unsigned int* p0     = (unsigned int*)alloc(npad * 128);
    unsigned int* vmax   = (unsigned int*)alloc((size_t)CANVASv * 256);
    double*       md0    = (double*)alloc(105 * 8 + 128 * 4); // md0 + s1 contiguous for one memset
    float*        s1     = (float*)(((char*)md0) + 105 * 8);
    float*        M1     = (float*)alloc(16384 * 4);
    float*        sc0    = (float*)alloc(64 * 4);
    float*        sh0    = (float*)alloc(64 * 4);
    float*        sc1    = (float*)alloc(128 * 4);
    float*        sh1    = (float*)alloc(128 * 4);
    float*        partials = (float*)alloc((size_t)MB1 * 16384 * 4);
    if (off > ws_size) return;

    hipMemsetAsync(counts, 0, (size_t)CANVASv * 4 * 5, stream);
    hipMemsetAsync(vmax, 0, (size_t)CANVASv * 256, stream);
    hipMemsetAsync(md0, 0, 105 * 8 + 128 * 4, stream);

    int blocksN = (n + 255) / 256;
    k_scatter1<<<blocksN, 256, 0, stream>>>((const float4*)feat, (const int4*)coor, vidx, counts, sumc, n);
    k_scatter2<<<blocksN, 256, 0, stream>>>((const float4*)feat, vidx, counts, sumc, spd, n);
    k_prex<<<512, 256, 0, stream>>>((const float4*)feat, (const int4*)coor, vidx, counts, sumc, spd, x, md0, n);
    k_fin0<<<1, 64, 0, stream>>>(md0, W0, g0, b0, sc0, sh0, n);
    k_gemm0<<<(2 * n + 255) / 256, 256, 0, stream>>>(x, W0, vidx, sc0, sh0, p0, vmax, n);
    int nchunks = (n + 31) / 32;
    k_moment1<<<MB1, 256, 0, stream>>>(p0, (const float*)vmax, vidx, partials, s1, n, nchunks);
    k_redM1<<<64, 256, 0, stream>>>(partials, M1);
    k_fin1<<<32, 256, 0, stream>>>(M1, s1, W1, g1, b1, sc1, sh1, n);
    int ntiles = (n + 127) / 128;
    hipFuncSetAttribute((const void*)k_fused, hipFuncAttributeMaxDynamicSharedMemorySize, FUSED_LDS);
    k_fused<<<256, 512, FUSED_LDS, stream>>>(p0, (const float*)vmax, vidx, x, W1, Wsp, bsp, sc1, sh1, outp, n, ntiles);
}

// Round 3
// 1409.288 us; speedup vs baseline: 2.4683x; 2.4683x over previous
//
#include <hip/hip_runtime.h>
#include <hip/hip_bf16.h>

#define NZv 1
#define NYv 400
#define NXv 352
#define Bv 4
#define CANVASv (Bv * NZv * NYv * NXv) /* 563200 */
#define EPSF 0.001f
#define VXF 0.2f
#define VYF 0.2f
#define VZF 4.0f
#define XOFFv 0.1f
#define YOFFv -39.9f
#define ZOFFv -1.0f

typedef __attribute__((ext_vector_type(8))) short bf16x8;
typedef __attribute__((ext_vector_type(4))) float f32x4;

__device__ __forceinline__ short f2bf(float f) {
    union { __hip_bfloat16 h; short s; } u;
    u.h = __float2bfloat16(f);
    return u.s;
}
__device__ __forceinline__ float bf2f(short s) {
    return __uint_as_float(((unsigned int)(unsigned short)s) << 16);
}
__device__ __forceinline__ unsigned int pk(float a, float b) {
    return (unsigned int)(unsigned short)f2bf(a) | ((unsigned int)(unsigned short)f2bf(b) << 16);
}

// ---------------- scatter pass 1: count + coord sums + first-touch vmax zero ----------------
__global__ void k_scatter1(const float4* __restrict__ feat, const int4* __restrict__ coors,
                           int* __restrict__ vidx, float* __restrict__ counts,
                           float* __restrict__ sumc, unsigned int* __restrict__ vmax, int n)
{
    int i = blockIdx.x * blockDim.x + threadIdx.x;
    if (i >= n) return;
    int4 c = coors[i];
    int v = ((c.x * NZv + c.y) * NYv + c.z) * NXv + c.w;
    vidx[i] = v;
    float4 f = feat[i];
    float old = atomicAdd(&counts[v], 1.0f);
    if (old == 0.0f) {
        uint4 z = make_uint4(0u, 0u, 0u, 0u);
        uint4* row = (uint4*)(vmax + (size_t)v * 64);
#pragma unroll
        for (int q = 0; q < 16; ++q) row[q] = z;
    }
    atomicAdd(&sumc[3 * v + 0], f.x);
    atomicAdd(&sumc[3 * v + 1], f.y);
    atomicAdd(&sumc[3 * v + 2], f.z);
}

// ---------------- scatter pass 2: mean-dist sums ----------------
__global__ void k_scatter2(const float4* __restrict__ feat, const int* __restrict__ vidx,
                           const float* __restrict__ counts, const float* __restrict__ sumc,
                           float* __restrict__ spd, int n)
{
    int i = blockIdx.x * blockDim.x + threadIdx.x;
    if (i >= n) return;
    int v = vidx[i];
    float safe = fmaxf(counts[v], 1.0f);
    float inv = 1.0f / safe;
    float4 f = feat[i];
    float dx = f.x - sumc[3 * v + 0] * inv;
    float dy = f.y - sumc[3 * v + 1] * inv;
    float dz = f.z - sumc[3 * v + 2] * inv;
    atomicAdd(&spd[v], sqrtf(dx * dx + dy * dy + dz * dz));
}

// ---------------- prex: build x bf16[n][16] + 14x14 moment accumulation ----------------
__global__ __launch_bounds__(256, 2) void k_prex(const float4* __restrict__ feat,
                       const int4* __restrict__ coors,
                       const int* __restrict__ vidx, const float* __restrict__ counts,
                       const float* __restrict__ sumc, const float* __restrict__ spd,
                       unsigned int* __restrict__ x, double* __restrict__ md0, int n)
{
    float mv[105];
#pragma unroll
    for (int e = 0; e < 105; ++e) mv[e] = 0.f;
    int t = threadIdx.x;
    int stride = gridDim.x * blockDim.x;
    for (int i = blockIdx.x * blockDim.x + t; i < n; i += stride) {
        float4 f = feat[i];
        int4 c = coors[i];
        int v = vidx[i];
        float safe = fmaxf(counts[v], 1.0f);
        float inv = 1.0f / safe;
        float vals[14];
        vals[0] = f.x; vals[1] = f.y; vals[2] = f.z; vals[3] = f.w;
        vals[4] = safe / 0.16f;
        vals[5] = spd[v] * inv;
        vals[6] = f.x - sumc[3 * v + 0] * inv;
        vals[7] = f.y - sumc[3 * v + 1] * inv;
        vals[8] = f.z - sumc[3 * v + 2] * inv;
        vals[9]  = f.x - ((float)c.w * VXF + XOFFv);
        vals[10] = f.y - ((float)c.z * VYF + YOFFv);
        vals[11] = f.z - ((float)c.y * VZF + ZOFFv);
        vals[12] = sqrtf(f.x * f.x + f.y * f.y + f.z * f.z);
        vals[13] = 1.0f;
        int idx = 0;
#pragma unroll
        for (int a = 0; a < 14; ++a)
#pragma unroll
            for (int b = a; b < 14; ++b) { mv[idx] = fmaf(vals[a], vals[b], mv[idx]); ++idx; }
        unsigned int row[8];
#pragma unroll
        for (int q = 0; q < 6; ++q) row[q] = pk(vals[2 * q], vals[2 * q + 1]);
        row[6] = pk(vals[12], 0.f);
        row[7] = 0u;
        uint4* dst = (uint4*)(x + (size_t)i * 8);
        dst[0] = make_uint4(row[0], row[1], row[2], row[3]);
        dst[1] = make_uint4(row[4], row[5], row[6], row[7]);
    }
    __shared__ float wacc[4][105];
    int lane = t & 63, wid = t >> 6;
#pragma unroll
    for (int e = 0; e < 105; ++e) {
        float v = mv[e];
        for (int m = 1; m < 64; m <<= 1) v += __shfl_xor(v, m);
        if (lane == 0) wacc[wid][e] = v;
    }
    __syncthreads();
    if (t < 105) {
        double s = (double)wacc[0][t] + (double)wacc[1][t] + (double)wacc[2][t] + (double)wacc[3][t];
        atomicAdd(&md0[t], s);
    }
}

__device__ __forceinline__ int idx14(int a, int b) { // a<=b
    return a * 14 - a * (a - 1) / 2 + (b - a);
}

// ---------------- fin0: BN0 scale/shift from moments ----------------
__global__ void k_fin0(const double* __restrict__ md0, const float* __restrict__ W0,
                       const float* __restrict__ g0, const float* __restrict__ b0,
                       float* __restrict__ sc0, float* __restrict__ sh0, int n)
{
    __shared__ double mom[105];
    int t = threadIdx.x;
    for (int e = t; e < 105; e += 64) mom[e] = md0[e];
    __syncthreads();
    double nn = (double)n;
    double mu[13];
#pragma unroll
    for (int j = 0; j < 13; ++j) mu[j] = mom[idx14(j, 13)] / nn;
    double wc[13];
#pragma unroll
    for (int j = 0; j < 13; ++j) wc[j] = (double)W0[j * 64 + t];
    double meanc = 0.0, var = 0.0;
#pragma unroll
    for (int j = 0; j < 13; ++j) {
        meanc += mu[j] * wc[j];
        for (int k = 0; k < 13; ++k) {
            int a = j < k ? j : k, b = j < k ? k : j;
            double cov = mom[idx14(a, b)] / nn - mu[j] * mu[k];
            var += cov * wc[j] * wc[k];
        }
    }
    float scale = g0[t] * rsqrtf((float)var + EPSF);
    sc0[t] = scale;
    sh0[t] = b0[t] - (float)meanc * scale;
}

// ---------------- vmax0: recompute p0 -> atomicMax/store into vmax ----------------
__global__ __launch_bounds__(256) void k_vmax0(const unsigned int* __restrict__ x,
    const float* __restrict__ W0, const int* __restrict__ vidx, const float* __restrict__ counts,
    const float* __restrict__ sc0, const float* __restrict__ sh0,
    unsigned int* __restrict__ vmax, int n)
{
    __shared__ float sW[13][64];
    __shared__ float ssc[64], ssh[64];
    int t = threadIdx.x;
    for (int e = t; e < 13 * 64; e += 256) sW[e >> 6][e & 63] = W0[e];
    if (t < 64) { ssc[t] = sc0[t]; ssh[t] = sh0[t]; }
    __syncthreads();
    int gid = blockIdx.x * 256 + t;
    int i = gid >> 1, half = gid & 1;
    if (i >= n) return;
    const uint4* xr = (const uint4*)(x + (size_t)i * 8);
    uint4 r0 = xr[0], r1 = xr[1];
    unsigned int rw[8] = {r0.x, r0.y, r0.z, r0.w, r1.x, r1.y, r1.z, r1.w};
    float vals[13];
#pragma unroll
    for (int k = 0; k < 13; ++k)
        vals[k] = bf2f((short)((k & 1) ? (rw[k >> 1] >> 16) : (rw[k >> 1] & 0xFFFF)));
    float acc[32];
#pragma unroll
    for (int c = 0; c < 32; ++c) acc[c] = 0.f;
#pragma unroll
    for (int k = 0; k < 13; ++k) {
        float xk = vals[k];
#pragma unroll
        for (int c = 0; c < 32; ++c) acc[c] = fmaf(xk, sW[k][half * 32 + c], acc[c]);
    }
    int v = vidx[i];
    float pv[32];
#pragma unroll
    for (int c = 0; c < 32; ++c) {
        int ch = half * 32 + c;
        pv[c] = fmaxf(fmaf(acc[c], ssc[ch], ssh[ch]), 0.f);
    }
    unsigned int* vrow = vmax + (size_t)v * 64 + half * 32;
    if (counts[v] == 1.0f) {
        // sole point of this voxel: plain vectorized store
        uint4* dst = (uint4*)vrow;
#pragma unroll
        for (int q = 0; q < 8; ++q)
            dst[q] = make_uint4(__float_as_uint(pv[4 * q]), __float_as_uint(pv[4 * q + 1]),
                                __float_as_uint(pv[4 * q + 2]), __float_as_uint(pv[4 * q + 3]));
    } else {
#pragma unroll
        for (int c = 0; c < 32; ++c) atomicMax(&vrow[c], __float_as_uint(pv[c]));
    }
}

// ---------------- gemm1s: X1=[p0(recomputed)|vmax] @ W1 -> y1 bf16 ----------------
#define G1_SW1 0
#define G1_SX  32768
#define G1_SW0 65536
#define G1_SCL (65536 + 3328)
#define G1_LDS (G1_SCL + 512)

__global__ __launch_bounds__(512) void k_gemm1s(const unsigned int* __restrict__ x,
    const float* __restrict__ W0f, const float* __restrict__ sc0, const float* __restrict__ sh0,
    const float* __restrict__ vmaxf, const int* __restrict__ vidx,
    const float* __restrict__ W1, unsigned int* __restrict__ y1, int n, int ntiles)
{
    extern __shared__ char lds[];
    char* sW1 = lds + G1_SW1;
    char* sx  = lds + G1_SX;
    float* sW0 = (float*)(lds + G1_SW0);
    float* ssc = (float*)(lds + G1_SCL);
    float* ssh = ssc + 64;
    int t = threadIdx.x, lane = t & 63, w = t >> 6;
    int pl = lane & 15, qd = lane >> 4;

    // stage W1 (128x128 f32, [k][c]) -> sW1[c][k] bf16, stride 256B, XOR swizzle
#pragma unroll
    for (int it = 0; it < 8; ++it) {
        int e = (it * 512 + t) * 4;
        float4 wv = *(const float4*)(W1 + e);
        int k = e >> 7, c0 = e & 127;
        float wa[4] = {wv.x, wv.y, wv.z, wv.w};
#pragma unroll
        for (int qq = 0; qq < 4; ++qq) {
            int c = c0 + qq;
            *(short*)(sW1 + c * 256 + ((k * 2) ^ ((c & 7) << 4))) = f2bf(wa[qq]);
        }
    }
    for (int e = t; e < 13 * 64; e += 512) sW0[e] = W0f[e];
    if (t < 64) { ssc[t] = sc0[t]; ssh[t] = sh0[t]; }
    __syncthreads();

    unsigned int szr = (unsigned int)(pl & 7) << 4;
    int rb_ = w * 16 + pl;
    for (int tile = blockIdx.x; tile < ntiles; tile += gridDim.x) {
        int base = tile * 128;
        {
            int p = t >> 2, s = t & 3;
            int i = base + p;
            char* rowp = sx + p * 256;
            unsigned int sz = (unsigned int)(p & 7) << 4;
            unsigned int ow[16];
            if (i < n) {
                if (s < 2) {
                    // recompute p0 channels [s*32, s*32+32)
                    const uint4* xr = (const uint4*)(x + (size_t)i * 8);
                    uint4 xr0 = xr[0], xr1 = xr[1];
                    unsigned int rw[8] = {xr0.x, xr0.y, xr0.z, xr0.w, xr1.x, xr1.y, xr1.z, xr1.w};
                    float vals[13];
#pragma unroll
                    for (int k = 0; k < 13; ++k)
                        vals[k] = bf2f((short)((k & 1) ? (rw[k >> 1] >> 16) : (rw[k >> 1] & 0xFFFF)));
                    float acc0[32];
#pragma unroll
                    for (int c = 0; c < 32; ++c) acc0[c] = 0.f;
#pragma unroll
                    for (int k = 0; k < 13; ++k) {
                        float xk = vals[k];
#pragma unroll
                        for (int c = 0; c < 32; ++c)
                            acc0[c] = fmaf(xk, sW0[k * 64 + s * 32 + c], acc0[c]);
                    }
#pragma unroll
                    for (int qq = 0; qq < 16; ++qq) {
                        int c0_ = s * 32 + 2 * qq;
                        float pa = fmaxf(fmaf(acc0[2 * qq], ssc[c0_], ssh[c0_]), 0.f);
                        float pb = fmaxf(fmaf(acc0[2 * qq + 1], ssc[c0_ + 1], ssh[c0_ + 1]), 0.f);
                        ow[qq] = pk(pa, pb);
                    }
                } else {
                    const float4* src = (const float4*)(vmaxf + (size_t)vidx[i] * 64 + (s - 2) * 32);
#pragma unroll
                    for (int qq = 0; qq < 8; ++qq) {
                        float4 f = src[qq];
                        ow[2 * qq]     = pk(f.x, f.y);
                        ow[2 * qq + 1] = pk(f.z, f.w);
                    }
                }
            } else {
#pragma unroll
                for (int qq = 0; qq < 16; ++qq) ow[qq] = 0u;
            }
            int k2 = s * 64;
#pragma unroll
            for (int qq = 0; qq < 4; ++qq)
                *(uint4*)(rowp + ((k2 + 16 * qq) ^ sz)) =
                    make_uint4(ow[4 * qq], ow[4 * qq + 1], ow[4 * qq + 2], ow[4 * qq + 3]);
        }
        __syncthreads();
        // MFMA: D[row=channel][col=point]  (a=W-frag, b=x-frag)
        f32x4 acc[8];
#pragma unroll
        for (int cb = 0; cb < 8; ++cb) acc[cb] = (f32x4){0.f, 0.f, 0.f, 0.f};
#pragma unroll
        for (int kc = 0; kc < 4; ++kc) {
            int ko2 = kc * 64 + qd * 16;
            bf16x8 b = *(bf16x8*)(sx + rb_ * 256 + (ko2 ^ szr));
#pragma unroll
            for (int cb = 0; cb < 8; ++cb) {
                int ra_ = cb * 16 + pl;
                bf16x8 a = *(bf16x8*)(sW1 + ra_ * 256 + (ko2 ^ szr));
                acc[cb] = __builtin_amdgcn_mfma_f32_16x16x32_bf16(a, b, acc[cb], 0, 0, 0);
            }
        }
        int pt = base + rb_;
        if (pt < n) {
            char* yrow = (char*)y1 + (size_t)pt * 256 + qd * 8;
#pragma unroll
            for (int cb = 0; cb < 8; ++cb) {
                uint2 o;
                o.x = pk(acc[cb][0], acc[cb][1]);
                o.y = pk(acc[cb][2], acc[cb][3]);
                *(uint2*)(yrow + cb * 32) = o;
            }
        }
        __syncthreads();
    }
}

// ---------------- stats over y1 bf16: per-channel sum/sumsq ----------------
__global__ __launch_bounds__(256) void k_stats1(const uint4* __restrict__ y1,
    double* __restrict__ s1d, double* __restrict__ sq1d, int n4)
{
    int tid = blockIdx.x * 256 + threadIdx.x;
    int stride = gridDim.x * 256;
    float s[8], q[8];
#pragma unroll
    for (int j = 0; j < 8; ++j) { s[j] = 0.f; q[j] = 0.f; }
    for (int u = tid; u < n4; u += stride) {
        uint4 d = y1[u];
        unsigned int ww[4] = {d.x, d.y, d.z, d.w};
#pragma unroll
        for (int m = 0; m < 4; ++m) {
            float a = bf2f((short)(ww[m] & 0xFFFF));
            float b = bf2f((short)(ww[m] >> 16));
            s[2 * m] += a;     q[2 * m]     = fmaf(a, a, q[2 * m]);
            s[2 * m + 1] += b; q[2 * m + 1] = fmaf(b, b, q[2 * m + 1]);
        }
    }
    int t = threadIdx.x, lane = t & 63;
    __shared__ float ls[4][128], lq[4][128];
#pragma unroll
    for (int j = 0; j < 8; ++j) {
        float sv = s[j] + __shfl_xor(s[j], 16); sv += __shfl_xor(sv, 32);
        float qv = q[j] + __shfl_xor(q[j], 16); qv += __shfl_xor(qv, 32);
        if (lane < 16) { int c = lane * 8 + j; ls[t >> 6][c] = sv; lq[t >> 6][c] = qv; }
    }
    __syncthreads();
    if (t < 128) {
        double sv = (double)ls[0][t] + ls[1][t] + ls[2][t] + ls[3][t];
        double qv = (double)lq[0][t] + lq[1][t] + lq[2][t] + lq[3][t];
        atomicAdd(&s1d[t], sv);
        atomicAdd(&sq1d[t], qv);
    }
}

__global__ void k_fin1s(const double* __restrict__ s1d, const double* __restrict__ sq1d,
                        const float* __restrict__ g1, const float* __restrict__ b1,
                        float* __restrict__ sc1, float* __restrict__ sh1, int n)
{
    int c = threadIdx.x;
    double mean = s1d[c] / (double)n;
    double var = sq1d[c] / (double)n - mean * mean;
    float scale = g1[c] * rsqrtf((float)var + EPSF);
    sc1[c] = scale;
    sh1[c] = b1[c] - (float)mean * scale;
}

// ---------------- fused2: BN+ReLU(y1) |fsp -> @ Ws + bs -> ReLU -> out ----------------
#define F2_SWS 0
#define F2_SX  49152
#define F2_SCL (49152 + 24576)
#define F2_LDS (F2_SCL + 1536)

__global__ __launch_bounds__(256) void k_fused2(const uint4* __restrict__ y1,
    const unsigned int* __restrict__ x,
    const float* __restrict__ Wsp, const float* __restrict__ bsp,
    const float* __restrict__ sc1, const float* __restrict__ sh1,
    float* __restrict__ out, int n, int ntiles)
{
    extern __shared__ char lds[];
    char* sWs = lds + F2_SWS;
    char* sx  = lds + F2_SX;
    float* ssc = (float*)(lds + F2_SCL);
    float* ssh = ssc + 128;
    float* sbs = ssh + 128;
    int t = threadIdx.x, lane = t & 63, w = t >> 6;
    int pl = lane & 15, qd = lane >> 4;

    // stage Ws (130x128 f32 [k][c]) -> sWs[c][k] bf16, stride 384B, swizzled
    for (int it = 0; it < 17; ++it) {
        int e = (it * 256 + t) * 4;
        if (e < 16640) {
            float4 wv = *(const float4*)(Wsp + e);
            int k = e >> 7, c0 = e & 127;
            float wa[4] = {wv.x, wv.y, wv.z, wv.w};
#pragma unroll
            for (int qq = 0; qq < 4; ++qq) {
                int c = c0 + qq;
                *(short*)(sWs + c * 384 + ((k * 2) ^ ((c & 7) << 4))) = f2bf(wa[qq]);
            }
        }
    }
    // zero-pad k2 in [260,320) for sWs (128 rows) and sx (64 rows)
    for (int e = t; e < 128 * 15; e += 256) {
        int r = e / 15, qq = e - r * 15;
        int k2 = 260 + 4 * qq;
        *(unsigned int*)(sWs + r * 384 + (k2 ^ ((r & 7) << 4))) = 0u;
    }
    for (int e = t; e < 64 * 15; e += 256) {
        int r = e / 15, qq = e - r * 15;
        int k2 = 260 + 4 * qq;
        *(unsigned int*)(sx + r * 384 + (k2 ^ ((r & 7) << 4))) = 0u;
    }
    if (t < 128) { ssc[t] = sc1[t]; ssh[t] = sh1[t]; sbs[t] = bsp[t]; }
    __syncthreads();

    unsigned int szr = (unsigned int)(pl & 7) << 4;
    int rb_ = w * 16 + pl;
    for (int tile = blockIdx.x; tile < ntiles; tile += gridDim.x) {
        int base = tile * 64;
        {
            int p = t >> 2, s = t & 3;
            int i = base + p;
            char* rowp = sx + p * 384;
            unsigned int sz = (unsigned int)(p & 7) << 4;
            unsigned int ow[16];
            if (i < n) {
                const uint4* src = (const uint4*)((const char*)y1 + (size_t)i * 256 + s * 64);
                uint4 d0 = src[0], d1 = src[1], d2 = src[2], d3 = src[3];
                unsigned int iw[16] = {d0.x, d0.y, d0.z, d0.w, d1.x, d1.y, d1.z, d1.w,
                                       d2.x, d2.y, d2.z, d2.w, d3.x, d3.y, d3.z, d3.w};
#pragma unroll
                for (int qq = 0; qq < 16; ++qq) {
                    int c = s * 32 + 2 * qq;
                    float a = fmaxf(fmaf(bf2f((short)(iw[qq] & 0xFFFF)), ssc[c], ssh[c]), 0.f);
                    float b = fmaxf(fmaf(bf2f((short)(iw[qq] >> 16)), ssc[c + 1], ssh[c + 1]), 0.f);
                    ow[qq] = pk(a, b);
                }
            } else {
#pragma unroll
                for (int qq = 0; qq < 16; ++qq) ow[qq] = 0u;
            }
            int k2 = s * 64;
#pragma unroll
            for (int qq = 0; qq < 4; ++qq)
                *(uint4*)(rowp + ((k2 + 16 * qq) ^ sz)) =
                    make_uint4(ow[4 * qq], ow[4 * qq + 1], ow[4 * qq + 2], ow[4 * qq + 3]);
        }
        if (t < 64) {
            int i = base + t; if (i >= n) i = n - 1;
            unsigned int fs = x[(size_t)i * 8 + 2]; // density, mdist bf16 pair
            *(unsigned int*)(sx + t * 384 + (256 ^ ((t & 7) << 4))) = fs;
        }
        __syncthreads();
        f32x4 acc[8];
#pragma unroll
        for (int cb = 0; cb < 8; ++cb) acc[cb] = (f32x4){0.f, 0.f, 0.f, 0.f};
#pragma unroll
        for (int kc = 0; kc < 5; ++kc) {
            int ko2 = kc * 64 + qd * 16;
            bf16x8 b = *(bf16x8*)(sx + rb_ * 384 + (ko2 ^ szr));
#pragma unroll
            for (int cb = 0; cb < 8; ++cb) {
                int ra_ = cb * 16 + pl;
                bf16x8 a = *(bf16x8*)(sWs + ra_ * 384 + (ko2 ^ szr));
                acc[cb] = __builtin_amdgcn_mfma_f32_16x16x32_bf16(a, b, acc[cb], 0, 0, 0);
            }
        }
        int pt = base + rb_;
        if (pt < n) {
            float* orow = out + (size_t)pt * 128 + qd * 4;
#pragma unroll
            for (int cb = 0; cb < 8; ++cb) {
                float4 bb = *(float4*)(sbs + cb * 16 + qd * 4);
                float4 o;
                o.x = fmaxf(acc[cb][0] + bb.x, 0.f);
                o.y = fmaxf(acc[cb][1] + bb.y, 0.f);
                o.z = fmaxf(acc[cb][2] + bb.z, 0.f);
                o.w = fmaxf(acc[cb][3] + bb.w, 0.f);
                *(float4*)(orow + cb * 16) = o;
            }
        }
        __syncthreads();
    }
}

extern "C" void kernel_launch(void* const* d_in, const int* in_sizes, int n_in,
                              void* d_out, int out_size, void* d_ws, size_t ws_size,
                              hipStream_t stream)
{
    const float* feat = (const float*)d_in[0];
    const int*   coor = (const int*)d_in[1];
    const float* W0   = (const float*)d_in[2];
    const float* g0   = (const float*)d_in[3];
    const float* b0   = (const float*)d_in[4];
    const float* W1   = (const float*)d_in[5];
    const float* g1   = (const float*)d_in[6];
    const float* b1   = (const float*)d_in[7];
    const float* Wsp  = (const float*)d_in[8];
    const float* bsp  = (const float*)d_in[9];
    float* outp = (float*)d_out;

    int n = in_sizes[0] / 4;
    size_t npad = ((size_t)n + 127) & ~127ULL;

    char* ws = (char*)d_ws;
    size_t off = 0;
    auto alloc = [&](size_t bytes) { char* p = ws + off; off = (off + bytes + 255) & ~255ULL; return p; };
    int*          vidx   = (int*)alloc(npad * 4);
    float*        counts = (float*)alloc((size_t)CANVASv * 4);
    float*        sumc   = (float*)alloc((size_t)CANVASv * 12);
    float*        spd    = (float*)alloc((size_t)CANVASv * 4);
    unsigned int* x      = (unsigned int*)alloc(npad * 32);
    unsigned int* vmax   = (unsigned int*)alloc((size_t)CANVASv * 256);
    unsigned int* y1     = (unsigned int*)alloc(npad * 256);
    double*       md0    = (double*)alloc(105 * 8 + 256 * 8);
    double*       s1d    = (double*)((char*)md0 + 105 * 8);
    double*       sq1d   = s1d + 128;
    float*        sc0    = (float*)alloc(64 * 4);
    float*        sh0    = (float*)alloc(64 * 4);
    float*        sc1    = (float*)alloc(128 * 4);
    float*        sh1    = (float*)alloc(128 * 4);
    if (off > ws_size) return;

    hipMemsetAsync(counts, 0, (size_t)CANVASv * 4 * 5, stream);
    hipMemsetAsync(md0, 0, 105 * 8 + 256 * 8, stream);

    int blocksN = (n + 255) / 256;
    k_scatter1<<<blocksN, 256, 0, stream>>>((const float4*)feat, (const int4*)coor, vidx, counts, sumc, vmax, n);
    k_scatter2<<<blocksN, 256, 0, stream>>>((const float4*)feat, vidx, counts, sumc, spd, n);
    k_prex<<<512, 256, 0, stream>>>((const float4*)feat, (const int4*)coor, vidx, counts, sumc, spd, x, md0, n);
    k_fin0<<<1, 64, 0, stream>>>(md0, W0, g0, b0, sc0, sh0, n);
    k_vmax0<<<(2 * n + 255) / 256, 256, 0, stream>>>(x, W0, vidx, counts, sc0, sh0, vmax, n);

    int ntiles1 = (n + 127) / 128;
    hipFuncSetAttribute((const void*)k_gemm1s, hipFuncAttributeMaxDynamicSharedMemorySize, G1_LDS);
    k_gemm1s<<<512, 512, G1_LDS, stream>>>(x, W0, sc0, sh0, (const float*)vmax, vidx, W1, y1, n, ntiles1);

    k_stats1<<<1024, 256, 0, stream>>>((const uint4*)y1, s1d, sq1d, n * 16);
    k_fin1s<<<1, 128, 0, stream>>>(s1d, sq1d, g1, b1, sc1, sh1, n);

    int ntiles2 = (n + 63) / 64;
    hipFuncSetAttribute((const void*)k_fused2, hipFuncAttributeMaxDynamicSharedMemorySize, F2_LDS);
    k_fused2<<<512, 256, F2_LDS, stream>>>((const uint4*)y1, x, Wsp, bsp, sc1, sh1, outp, n, ntiles2);
}

// Round 4
// 695.130 us; speedup vs baseline: 5.0042x; 2.0274x over previous
//
#include <hip/hip_runtime.h>
#include <hip/hip_bf16.h>

#define NZv 1
#define NYv 400
#define NXv 352
#define Bv 4
#define CANVASv (Bv * NZv * NYv * NXv) /* 563200 = 550 * 1024 */
#define EPSF 0.001f
#define VXF 0.2f
#define VYF 0.2f
#define VZF 4.0f
#define XOFFv 0.1f
#define YOFFv -39.9f
#define ZOFFv -1.0f

typedef __attribute__((ext_vector_type(8))) short bf16x8;
typedef __attribute__((ext_vector_type(4))) float f32x4;

__device__ __forceinline__ short f2bf(float f) {
    union { __hip_bfloat16 h; short s; } u;
    u.h = __float2bfloat16(f);
    return u.s;
}
__device__ __forceinline__ float bf2f(short s) {
    return __uint_as_float(((unsigned int)(unsigned short)s) << 16);
}
__device__ __forceinline__ unsigned int pk(float a, float b) {
    return (unsigned int)(unsigned short)f2bf(a) | ((unsigned int)(unsigned short)f2bf(b) << 16);
}

// ---------------- scatter pass 1: count + coord sums ----------------
__global__ void k_scatter1(const float4* __restrict__ feat, const int4* __restrict__ coors,
                           int* __restrict__ vidx, float* __restrict__ counts,
                           float* __restrict__ sumc, int n)
{
    int i = blockIdx.x * blockDim.x + threadIdx.x;
    if (i >= n) return;
    int4 c = coors[i];
    int v = ((c.x * NZv + c.y) * NYv + c.z) * NXv + c.w;
    vidx[i] = v;
    float4 f = feat[i];
    atomicAdd(&counts[v], 1.0f);
    atomicAdd(&sumc[3 * v + 0], f.x);
    atomicAdd(&sumc[3 * v + 1], f.y);
    atomicAdd(&sumc[3 * v + 2], f.z);
}

// ---------------- scatter pass 2: mean-dist sums ----------------
__global__ void k_scatter2(const float4* __restrict__ feat, const int* __restrict__ vidx,
                           const float* __restrict__ counts, const float* __restrict__ sumc,
                           float* __restrict__ spd, int n)
{
    int i = blockIdx.x * blockDim.x + threadIdx.x;
    if (i >= n) return;
    int v = vidx[i];
    float safe = fmaxf(counts[v], 1.0f);
    float inv = 1.0f / safe;
    float4 f = feat[i];
    float dx = f.x - sumc[3 * v + 0] * inv;
    float dy = f.y - sumc[3 * v + 1] * inv;
    float dz = f.z - sumc[3 * v + 2] * inv;
    atomicAdd(&spd[v], sqrtf(dx * dx + dy * dy + dz * dz));
}

// ---------------- prex: build x bf16[n][16] + 14x14 moment accumulation ----------------
__global__ __launch_bounds__(256, 2) void k_prex(const float4* __restrict__ feat,
                       const int4* __restrict__ coors,
                       const int* __restrict__ vidx, const float* __restrict__ counts,
                       const float* __restrict__ sumc, const float* __restrict__ spd,
                       unsigned int* __restrict__ x, double* __restrict__ md0, int n)
{
    float mv[105];
#pragma unroll
    for (int e = 0; e < 105; ++e) mv[e] = 0.f;
    int t = threadIdx.x;
    int stride = gridDim.x * blockDim.x;
    for (int i = blockIdx.x * blockDim.x + t; i < n; i += stride) {
        float4 f = feat[i];
        int4 c = coors[i];
        int v = vidx[i];
        float safe = fmaxf(counts[v], 1.0f);
        float inv = 1.0f / safe;
        float vals[14];
        vals[0] = f.x; vals[1] = f.y; vals[2] = f.z; vals[3] = f.w;
        vals[4] = safe / 0.16f;
        vals[5] = spd[v] * inv;
        vals[6] = f.x - sumc[3 * v + 0] * inv;
        vals[7] = f.y - sumc[3 * v + 1] * inv;
        vals[8] = f.z - sumc[3 * v + 2] * inv;
        vals[9]  = f.x - ((float)c.w * VXF + XOFFv);
        vals[10] = f.y - ((float)c.z * VYF + YOFFv);
        vals[11] = f.z - ((float)c.y * VZF + ZOFFv);
        vals[12] = sqrtf(f.x * f.x + f.y * f.y + f.z * f.z);
        vals[13] = 1.0f;
        int idx = 0;
#pragma unroll
        for (int a = 0; a < 14; ++a)
#pragma unroll
            for (int b = a; b < 14; ++b) { mv[idx] = fmaf(vals[a], vals[b], mv[idx]); ++idx; }
        unsigned int row[8];
#pragma unroll
        for (int q = 0; q < 6; ++q) row[q] = pk(vals[2 * q], vals[2 * q + 1]);
        row[6] = pk(vals[12], 0.f);
        row[7] = 0u;
        uint4* dst = (uint4*)(x + (size_t)i * 8);
        dst[0] = make_uint4(row[0], row[1], row[2], row[3]);
        dst[1] = make_uint4(row[4], row[5], row[6], row[7]);
    }
    __shared__ float wacc[4][105];
    int lane = t & 63, wid = t >> 6;
#pragma unroll
    for (int e = 0; e < 105; ++e) {
        float v = mv[e];
        for (int m = 1; m < 64; m <<= 1) v += __shfl_xor(v, m);
        if (lane == 0) wacc[wid][e] = v;
    }
    __syncthreads();
    if (t < 105) {
        double s = (double)wacc[0][t] + (double)wacc[1][t] + (double)wacc[2][t] + (double)wacc[3][t];
        atomicAdd(&md0[t], s);
    }
}

__device__ __forceinline__ int idx14(int a, int b) { // a<=b
    return a * 14 - a * (a - 1) / 2 + (b - a);
}

// ---------------- fin0: BN0 scale/shift from moments ----------------
__global__ void k_fin0(const double* __restrict__ md0, const float* __restrict__ W0,
                       const float* __restrict__ g0, const float* __restrict__ b0,
                       float* __restrict__ sc0, float* __restrict__ sh0, int n)
{
    __shared__ double mom[105];
    int t = threadIdx.x;
    for (int e = t; e < 105; e += 64) mom[e] = md0[e];
    __syncthreads();
    double nn = (double)n;
    double mu[13];
#pragma unroll
    for (int j = 0; j < 13; ++j) mu[j] = mom[idx14(j, 13)] / nn;
    double wc[13];
#pragma unroll
    for (int j = 0; j < 13; ++j) wc[j] = (double)W0[j * 64 + t];
    double meanc = 0.0, var = 0.0;
#pragma unroll
    for (int j = 0; j < 13; ++j) {
        meanc += mu[j] * wc[j];
        for (int k = 0; k < 13; ++k) {
            int a = j < k ? j : k, b = j < k ? k : j;
            double cov = mom[idx14(a, b)] / nn - mu[j] * mu[k];
            var += cov * wc[j] * wc[k];
        }
    }
    float scale = g0[t] * rsqrtf((float)var + EPSF);
    sc0[t] = scale;
    sh0[t] = b0[t] - (float)meanc * scale;
}

// ---------------- scanA: per-1024-chunk exclusive scan of counts -> starts, chunk sums ----------------
__global__ __launch_bounds__(1024) void k_scanA(const float* __restrict__ counts,
                                                int* __restrict__ starts, int* __restrict__ bsum)
{
    __shared__ int sdata[1024];
    int t = threadIdx.x;
    int v = blockIdx.x * 1024 + t;
    int c = (int)counts[v];
    sdata[t] = c;
    __syncthreads();
#pragma unroll
    for (int off = 1; off < 1024; off <<= 1) {
        int val = (t >= off) ? sdata[t - off] : 0;
        __syncthreads();
        sdata[t] += val;
        __syncthreads();
    }
    starts[v] = sdata[t] - c; // exclusive
    if (t == 1023) bsum[blockIdx.x] = sdata[t];
}

// ---------------- scanB: exclusive scan of 550 chunk sums ----------------
__global__ __launch_bounds__(1024) void k_scanB(int* __restrict__ bsum, int* __restrict__ boff)
{
    __shared__ int sdata[1024];
    int t = threadIdx.x;
    int c = (t < 550) ? bsum[t] : 0;
    sdata[t] = c;
    __syncthreads();
#pragma unroll
    for (int off = 1; off < 1024; off <<= 1) {
        int val = (t >= off) ? sdata[t - off] : 0;
        __syncthreads();
        sdata[t] += val;
        __syncthreads();
    }
    if (t < 550) boff[t] = sdata[t] - c;
}

// ---------------- scanC: add chunk offsets ----------------
__global__ __launch_bounds__(1024) void k_scanC(int* __restrict__ starts, const int* __restrict__ boff)
{
    int v = blockIdx.x * 1024 + threadIdx.x;
    starts[v] += boff[blockIdx.x];
}

// ---------------- perm: counting-sort scatter (starts becomes INCLUSIVE prefix after this) ----------------
__global__ void k_perm(const int* __restrict__ vidx, int* __restrict__ starts,
                       int* __restrict__ perm, int n)
{
    int i = blockIdx.x * blockDim.x + threadIdx.x;
    if (i >= n) return;
    int pos = atomicAdd(&starts[vidx[i]], 1);
    perm[pos] = i;
}

// ---------------- vmaxv: per-voxel max of p0 (recomputed), wave per voxel, bf16 out ----------------
__global__ __launch_bounds__(256) void k_vmaxv(const unsigned int* __restrict__ x,
    const float* __restrict__ W0, const float* __restrict__ sc0, const float* __restrict__ sh0,
    const int* __restrict__ startsPost, const int* __restrict__ perm,
    unsigned int* __restrict__ vmaxb, int nvox)
{
    int t = threadIdx.x, lane = t & 63, wid = t >> 6;
    int v = blockIdx.x * 4 + wid;
    if (v >= nvox) return;
    int end = startsPost[v];
    int begin = (v > 0) ? startsPost[v - 1] : 0;
    if (begin == end) return;
    float wcol[13];
#pragma unroll
    for (int k = 0; k < 13; ++k) wcol[k] = W0[k * 64 + lane];
    float sc = sc0[lane], sh = sh0[lane];
    float m = 0.f;
    for (int j = begin; j < end; ++j) {
        int i = perm[j];
        const uint4* xr = (const uint4*)(x + (size_t)i * 8);
        uint4 r0 = xr[0], r1 = xr[1];
        unsigned int rw[8] = {r0.x, r0.y, r0.z, r0.w, r1.x, r1.y, r1.z, r1.w};
        float acc = 0.f;
#pragma unroll
        for (int k = 0; k < 13; ++k) {
            float xv = bf2f((short)((k & 1) ? (rw[k >> 1] >> 16) : (rw[k >> 1] & 0xFFFF)));
            acc = fmaf(xv, wcol[k], acc);
        }
        m = fmaxf(m, fmaxf(fmaf(acc, sc, sh), 0.f));
    }
    float mn = __shfl_xor(m, 1);
    if ((lane & 1) == 0)
        vmaxb[(size_t)v * 32 + (lane >> 1)] = pk(m, mn);
}

// ---------------- gemm1s: X1=[p0(recomputed)|vmax] @ W1 -> y1 bf16 ----------------
#define G1_SW1 0
#define G1_SX  32768
#define G1_SW0 65536
#define G1_SCL (65536 + 3328)
#define G1_LDS (G1_SCL + 512)

__global__ __launch_bounds__(512) void k_gemm1s(const unsigned int* __restrict__ x,
    const float* __restrict__ W0f, const float* __restrict__ sc0, const float* __restrict__ sh0,
    const unsigned int* __restrict__ vmaxb, const int* __restrict__ vidx,
    const float* __restrict__ W1, unsigned int* __restrict__ y1, int n, int ntiles)
{
    extern __shared__ char lds[];
    char* sW1 = lds + G1_SW1;
    char* sx  = lds + G1_SX;
    float* sW0 = (float*)(lds + G1_SW0);
    float* ssc = (float*)(lds + G1_SCL);
    float* ssh = ssc + 64;
    int t = threadIdx.x, lane = t & 63, w = t >> 6;
    int pl = lane & 15, qd = lane >> 4;

    // stage W1 (128x128 f32, [k][c]) -> sW1[c][k] bf16, stride 256B, XOR swizzle
#pragma unroll
    for (int it = 0; it < 8; ++it) {
        int e = (it * 512 + t) * 4;
        float4 wv = *(const float4*)(W1 + e);
        int k = e >> 7, c0 = e & 127;
        float wa[4] = {wv.x, wv.y, wv.z, wv.w};
#pragma unroll
        for (int qq = 0; qq < 4; ++qq) {
            int c = c0 + qq;
            *(short*)(sW1 + c * 256 + ((k * 2) ^ ((c & 7) << 4))) = f2bf(wa[qq]);
        }
    }
    for (int e = t; e < 13 * 64; e += 512) sW0[e] = W0f[e];
    if (t < 64) { ssc[t] = sc0[t]; ssh[t] = sh0[t]; }
    __syncthreads();

    unsigned int szr = (unsigned int)(pl & 7) << 4;
    int rb_ = w * 16 + pl;
    for (int tile = blockIdx.x; tile < ntiles; tile += gridDim.x) {
        int base = tile * 128;
        {
            int p = t >> 2, s = t & 3;
            int i = base + p;
            char* rowp = sx + p * 256;
            unsigned int sz = (unsigned int)(p & 7) << 4;
            unsigned int ow[16];
            if (i < n) {
                if (s < 2) {
                    const uint4* xr = (const uint4*)(x + (size_t)i * 8);
                    uint4 xr0 = xr[0], xr1 = xr[1];
                    unsigned int rw[8] = {xr0.x, xr0.y, xr0.z, xr0.w, xr1.x, xr1.y, xr1.z, xr1.w};
                    float vals[13];
#pragma unroll
                    for (int k = 0; k < 13; ++k)
                        vals[k] = bf2f((short)((k & 1) ? (rw[k >> 1] >> 16) : (rw[k >> 1] & 0xFFFF)));
                    float acc0[32];
#pragma unroll
                    for (int c = 0; c < 32; ++c) acc0[c] = 0.f;
#pragma unroll
                    for (int k = 0; k < 13; ++k) {
                        float xk = vals[k];
#pragma unroll
                        for (int c = 0; c < 32; ++c)
                            acc0[c] = fmaf(xk, sW0[k * 64 + s * 32 + c], acc0[c]);
                    }
#pragma unroll
                    for (int qq = 0; qq < 16; ++qq) {
                        int c0_ = s * 32 + 2 * qq;
                        float pa = fmaxf(fmaf(acc0[2 * qq], ssc[c0_], ssh[c0_]), 0.f);
                        float pb = fmaxf(fmaf(acc0[2 * qq + 1], ssc[c0_ + 1], ssh[c0_ + 1]), 0.f);
                        ow[qq] = pk(pa, pb);
                    }
                } else {
                    const uint4* src = (const uint4*)(vmaxb + (size_t)vidx[i] * 32 + (s - 2) * 16);
                    uint4 d0 = src[0], d1 = src[1], d2 = src[2], d3 = src[3];
                    ow[0] = d0.x; ow[1] = d0.y; ow[2] = d0.z; ow[3] = d0.w;
                    ow[4] = d1.x; ow[5] = d1.y; ow[6] = d1.z; ow[7] = d1.w;
                    ow[8] = d2.x; ow[9] = d2.y; ow[10] = d2.z; ow[11] = d2.w;
                    ow[12] = d3.x; ow[13] = d3.y; ow[14] = d3.z; ow[15] = d3.w;
                }
            } else {
#pragma unroll
                for (int qq = 0; qq < 16; ++qq) ow[qq] = 0u;
            }
            int k2 = s * 64;
#pragma unroll
            for (int qq = 0; qq < 4; ++qq)
                *(uint4*)(rowp + ((k2 + 16 * qq) ^ sz)) =
                    make_uint4(ow[4 * qq], ow[4 * qq + 1], ow[4 * qq + 2], ow[4 * qq + 3]);
        }
        __syncthreads();
        // MFMA: D[row=channel][col=point]  (a=W-frag, b=x-frag)
        f32x4 acc[8];
#pragma unroll
        for (int cb = 0; cb < 8; ++cb) acc[cb] = (f32x4){0.f, 0.f, 0.f, 0.f};
#pragma unroll
        for (int kc = 0; kc < 4; ++kc) {
            int ko2 = kc * 64 + qd * 16;
            bf16x8 b = *(bf16x8*)(sx + rb_ * 256 + (ko2 ^ szr));
#pragma unroll
            for (int cb = 0; cb < 8; ++cb) {
                int ra_ = cb * 16 + pl;
                bf16x8 a = *(bf16x8*)(sW1 + ra_ * 256 + (ko2 ^ szr));
                acc[cb] = __builtin_amdgcn_mfma_f32_16x16x32_bf16(a, b, acc[cb], 0, 0, 0);
            }
        }
        int pt = base + rb_;
        if (pt < n) {
            char* yrow = (char*)y1 + (size_t)pt * 256 + qd * 8;
#pragma unroll
            for (int cb = 0; cb < 8; ++cb) {
                uint2 o;
                o.x = pk(acc[cb][0], acc[cb][1]);
                o.y = pk(acc[cb][2], acc[cb][3]);
                *(uint2*)(yrow + cb * 32) = o;
            }
        }
        __syncthreads();
    }
}

// ---------------- stats over y1 bf16: per-channel sum/sumsq ----------------
__global__ __launch_bounds__(256) void k_stats1(const uint4* __restrict__ y1,
    double* __restrict__ s1d, double* __restrict__ sq1d, int n4)
{
    int tid = blockIdx.x * 256 + threadIdx.x;
    int stride = gridDim.x * 256;
    float s[8], q[8];
#pragma unroll
    for (int j = 0; j < 8; ++j) { s[j] = 0.f; q[j] = 0.f; }
    for (int u = tid; u < n4; u += stride) {
        uint4 d = y1[u];
        unsigned int ww[4] = {d.x, d.y, d.z, d.w};
#pragma unroll
        for (int m = 0; m < 4; ++m) {
            float a = bf2f((short)(ww[m] & 0xFFFF));
            float b = bf2f((short)(ww[m] >> 16));
            s[2 * m] += a;     q[2 * m]     = fmaf(a, a, q[2 * m]);
            s[2 * m + 1] += b; q[2 * m + 1] = fmaf(b, b, q[2 * m + 1]);
        }
    }
    int t = threadIdx.x, lane = t & 63;
    __shared__ float ls[4][128], lq[4][128];
#pragma unroll
    for (int j = 0; j < 8; ++j) {
        float sv = s[j] + __shfl_xor(s[j], 16); sv += __shfl_xor(sv, 32);
        float qv = q[j] + __shfl_xor(q[j], 16); qv += __shfl_xor(qv, 32);
        if (lane < 16) { int c = lane * 8 + j; ls[t >> 6][c] = sv; lq[t >> 6][c] = qv; }
    }
    __syncthreads();
    if (t < 128) {
        double sv = (double)ls[0][t] + ls[1][t] + ls[2][t] + ls[3][t];
        double qv = (double)lq[0][t] + lq[1][t] + lq[2][t] + lq[3][t];
        atomicAdd(&s1d[t], sv);
        atomicAdd(&sq1d[t], qv);
    }
}

__global__ void k_fin1s(const double* __restrict__ s1d, const double* __restrict__ sq1d,
                        const float* __restrict__ g1, const float* __restrict__ b1,
                        float* __restrict__ sc1, float* __restrict__ sh1, int n)
{
    int c = threadIdx.x;
    double mean = s1d[c] / (double)n;
    double var = sq1d[c] / (double)n - mean * mean;
    float scale = g1[c] * rsqrtf((float)var + EPSF);
    sc1[c] = scale;
    sh1[c] = b1[c] - (float)mean * scale;
}

// ---------------- fused2: BN+ReLU(y1) |fsp -> @ Ws + bs -> ReLU -> out ----------------
#define F2_SWS 0
#define F2_SX  49152
#define F2_SCL (49152 + 24576)
#define F2_LDS (F2_SCL + 1536)

__global__ __launch_bounds__(256) void k_fused2(const uint4* __restrict__ y1,
    const unsigned int* __restrict__ x,
    const float* __restrict__ Wsp, const float* __restrict__ bsp,
    const float* __restrict__ sc1, const float* __restrict__ sh1,
    float* __restrict__ out, int n, int ntiles)
{
    extern __shared__ char lds[];
    char* sWs = lds + F2_SWS;
    char* sx  = lds + F2_SX;
    float* ssc = (float*)(lds + F2_SCL);
    float* ssh = ssc + 128;
    float* sbs = ssh + 128;
    int t = threadIdx.x, lane = t & 63, w = t >> 6;
    int pl = lane & 15, qd = lane >> 4;

    for (int it = 0; it < 17; ++it) {
        int e = (it * 256 + t) * 4;
        if (e < 16640) {
            float4 wv = *(const float4*)(Wsp + e);
            int k = e >> 7, c0 = e & 127;
            float wa[4] = {wv.x, wv.y, wv.z, wv.w};
#pragma unroll
            for (int qq = 0; qq < 4; ++qq) {
                int c = c0 + qq;
                *(short*)(sWs + c * 384 + ((k * 2) ^ ((c & 7) << 4))) = f2bf(wa[qq]);
            }
        }
    }
    for (int e = t; e < 128 * 15; e += 256) {
        int r = e / 15, qq = e - r * 15;
        int k2 = 260 + 4 * qq;
        *(unsigned int*)(sWs + r * 384 + (k2 ^ ((r & 7) << 4))) = 0u;
    }
    for (int e = t; e < 64 * 15; e += 256) {
        int r = e / 15, qq = e - r * 15;
        int k2 = 260 + 4 * qq;
        *(unsigned int*)(sx + r * 384 + (k2 ^ ((r & 7) << 4))) = 0u;
    }
    if (t < 128) { ssc[t] = sc1[t]; ssh[t] = sh1[t]; sbs[t] = bsp[t]; }
    __syncthreads();

    unsigned int szr = (unsigned int)(pl & 7) << 4;
    int rb_ = w * 16 + pl;
    for (int tile = blockIdx.x; tile < ntiles; tile += gridDim.x) {
        int base = tile * 64;
        {
            int p = t >> 2, s = t & 3;
            int i = base + p;
            char* rowp = sx + p * 384;
            unsigned int sz = (unsigned int)(p & 7) << 4;
            unsigned int ow[16];
            if (i < n) {
                const uint4* src = (const uint4*)((const char*)y1 + (size_t)i * 256 + s * 64);
                uint4 d0 = src[0], d1 = src[1], d2 = src[2], d3 = src[3];
                unsigned int iw[16] = {d0.x, d0.y, d0.z, d0.w, d1.x, d1.y, d1.z, d1.w,
                                       d2.x, d2.y, d2.z, d2.w, d3.x, d3.y, d3.z, d3.w};
#pragma unroll
                for (int qq = 0; qq < 16; ++qq) {
                    int c = s * 32 + 2 * qq;
                    float a = fmaxf(fmaf(bf2f((short)(iw[qq] & 0xFFFF)), ssc[c], ssh[c]), 0.f);
                    float b = fmaxf(fmaf(bf2f((short)(iw[qq] >> 16)), ssc[c + 1], ssh[c + 1]), 0.f);
                    ow[qq] = pk(a, b);
                }
            } else {
#pragma unroll
                for (int qq = 0; qq < 16; ++qq) ow[qq] = 0u;
            }
            int k2 = s * 64;
#pragma unroll
            for (int qq = 0; qq < 4; ++qq)
                *(uint4*)(rowp + ((k2 + 16 * qq) ^ sz)) =
                    make_uint4(ow[4 * qq], ow[4 * qq + 1], ow[4 * qq + 2], ow[4 * qq + 3]);
        }
        if (t < 64) {
            int i = base + t; if (i >= n) i = n - 1;
            unsigned int fs = x[(size_t)i * 8 + 2];
            *(unsigned int*)(sx + t * 384 + (256 ^ ((t & 7) << 4))) = fs;
        }
        __syncthreads();
        f32x4 acc[8];
#pragma unroll
        for (int cb = 0; cb < 8; ++cb) acc[cb] = (f32x4){0.f, 0.f, 0.f, 0.f};
#pragma unroll
        for (int kc = 0; kc < 5; ++kc) {
            int ko2 = kc * 64 + qd * 16;
            bf16x8 b = *(bf16x8*)(sx + rb_ * 384 + (ko2 ^ szr));
#pragma unroll
            for (int cb = 0; cb < 8; ++cb) {
                int ra_ = cb * 16 + pl;
                bf16x8 a = *(bf16x8*)(sWs + ra_ * 384 + (ko2 ^ szr));
                acc[cb] = __builtin_amdgcn_mfma_f32_16x16x32_bf16(a, b, acc[cb], 0, 0, 0);
            }
        }
        int pt = base + rb_;
        if (pt < n) {
            float* orow = out + (size_t)pt * 128 + qd * 4;
#pragma unroll
            for (int cb = 0; cb < 8; ++cb) {
                float4 bb = *(float4*)(sbs + cb * 16 + qd * 4);
                float4 o;
                o.x = fmaxf(acc[cb][0] + bb.x, 0.f);
                o.y = fmaxf(acc[cb][1] + bb.y, 0.f);
                o.z = fmaxf(acc[cb][2] + bb.z, 0.f);
                o.w = fmaxf(acc[cb][3] + bb.w, 0.f);
                *(float4*)(orow + cb * 16) = o;
            }
        }
        __syncthreads();
    }
}

extern "C" void kernel_launch(void* const* d_in, const int* in_sizes, int n_in,
                              void* d_out, int out_size, void* d_ws, size_t ws_size,
                              hipStream_t stream)
{
    const float* feat = (const float*)d_in[0];
    const int*   coor = (const int*)d_in[1];
    const float* W0   = (const float*)d_in[2];
    const float* g0   = (const float*)d_in[3];
    const float* b0   = (const float*)d_in[4];
    const float* W1   = (const float*)d_in[5];
    const float* g1   = (const float*)d_in[6];
    const float* b1   = (const float*)d_in[7];
    const float* Wsp  = (const float*)d_in[8];
    const float* bsp  = (const float*)d_in[9];
    float* outp = (float*)d_out;

    int n = in_sizes[0] / 4;
    size_t npad = ((size_t)n + 127) & ~127ULL;

    char* ws = (char*)d_ws;
    size_t off = 0;
    auto alloc = [&](size_t bytes) { char* p = ws + off; off = (off + bytes + 255) & ~255ULL; return p; };
    int*          vidx   = (int*)alloc(npad * 4);
    float*        counts = (float*)alloc((size_t)CANVASv * 4);
    float*        sumc   = (float*)alloc((size_t)CANVASv * 12);
    float*        spd    = (float*)alloc((size_t)CANVASv * 4);
    unsigned int* x      = (unsigned int*)alloc(npad * 32);
    unsigned int* vmaxb  = (unsigned int*)alloc((size_t)CANVASv * 128);
    unsigned int* y1     = (unsigned int*)alloc(npad * 256);
    int*          starts = (int*)alloc((size_t)CANVASv * 4);
    int*          perm   = (int*)alloc(npad * 4);
    int*          bsum   = (int*)alloc(1024 * 4);
    int*          boff   = (int*)alloc(1024 * 4);
    double*       md0    = (double*)alloc(105 * 8 + 256 * 8);
    double*       s1d    = (double*)((char*)md0 + 105 * 8);
    double*       sq1d   = s1d + 128;
    float*        sc0    = (float*)alloc(64 * 4);
    float*        sh0    = (float*)alloc(64 * 4);
    float*        sc1    = (float*)alloc(128 * 4);
    float*        sh1    = (float*)alloc(128 * 4);
    if (off > ws_size) return;

    hipMemsetAsync(counts, 0, (size_t)CANVASv * 4 * 5, stream);
    hipMemsetAsync(md0, 0, 105 * 8 + 256 * 8, stream);

    int blocksN = (n + 255) / 256;
    k_scatter1<<<blocksN, 256, 0, stream>>>((const float4*)feat, (const int4*)coor, vidx, counts, sumc, n);
    k_scatter2<<<blocksN, 256, 0, stream>>>((const float4*)feat, vidx, counts, sumc, spd, n);
    k_prex<<<512, 256, 0, stream>>>((const float4*)feat, (const int4*)coor, vidx, counts, sumc, spd, x, md0, n);
    k_fin0<<<1, 64, 0, stream>>>(md0, W0, g0, b0, sc0, sh0, n);

    // counting sort by voxel
    k_scanA<<<CANVASv / 1024, 1024, 0, stream>>>(counts, starts, bsum);
    k_scanB<<<1, 1024, 0, stream>>>(bsum, boff);
    k_scanC<<<CANVASv / 1024, 1024, 0, stream>>>(starts, boff);
    k_perm<<<blocksN, 256, 0, stream>>>(vidx, starts, perm, n);
    // per-voxel max (starts is now inclusive prefix)
    k_vmaxv<<<(CANVASv + 3) / 4, 256, 0, stream>>>(x, W0, sc0, sh0, starts, perm, vmaxb, CANVASv);

    int ntiles1 = (n + 127) / 128;
    hipFuncSetAttribute((const void*)k_gemm1s, hipFuncAttributeMaxDynamicSharedMemorySize, G1_LDS);
    k_gemm1s<<<512, 512, G1_LDS, stream>>>(x, W0, sc0, sh0, vmaxb, vidx, W1, y1, n, ntiles1);

    k_stats1<<<1024, 256, 0, stream>>>((const uint4*)y1, s1d, sq1d, n * 16);
    k_fin1s<<<1, 128, 0, stream>>>(s1d, sq1d, g1, b1, sc1, sh1, n);

    int ntiles2 = (n + 63) / 64;
    hipFuncSetAttribute((const void*)k_fused2, hipFuncAttributeMaxDynamicSharedMemorySize, F2_LDS);
    k_fused2<<<512, 256, F2_LDS, stream>>>((const uint4*)y1, x, Wsp, bsp, sc1, sh1, outp, n, ntiles2);
}

// Round 5
// 597.158 us; speedup vs baseline: 5.8252x; 1.1641x over previous
//
#include <hip/hip_runtime.h>
#include <hip/hip_bf16.h>

#define NZv 1
#define NYv 400
#define NXv 352
#define Bv 4
#define CANVASv (Bv * NZv * NYv * NXv) /* 563200 = 550 * 1024 */
#define EPSF 0.001f
#define VXF 0.2f
#define VYF 0.2f
#define VZF 4.0f
#define XOFFv 0.1f
#define YOFFv -39.9f
#define ZOFFv -1.0f

typedef __attribute__((ext_vector_type(8))) short bf16x8;
typedef __attribute__((ext_vector_type(4))) float f32x4;

__device__ __forceinline__ short f2bf(float f) {
    union { __hip_bfloat16 h; short s; } u;
    u.h = __float2bfloat16(f);
    return u.s;
}
__device__ __forceinline__ float bf2f(short s) {
    return __uint_as_float(((unsigned int)(unsigned short)s) << 16);
}
__device__ __forceinline__ unsigned int pk(float a, float b) {
    return (unsigned int)(unsigned short)f2bf(a) | ((unsigned int)(unsigned short)f2bf(b) << 16);
}

// ---------------- scatter pass 1: count + coord sums ----------------
__global__ void k_scatter1(const float4* __restrict__ feat, const int4* __restrict__ coors,
                           int* __restrict__ vidx, float* __restrict__ counts,
                           float* __restrict__ sumc, int n)
{
    int i = blockIdx.x * blockDim.x + threadIdx.x;
    if (i >= n) return;
    int4 c = coors[i];
    int v = ((c.x * NZv + c.y) * NYv + c.z) * NXv + c.w;
    vidx[i] = v;
    float4 f = feat[i];
    atomicAdd(&counts[v], 1.0f);
    atomicAdd(&sumc[3 * v + 0], f.x);
    atomicAdd(&sumc[3 * v + 1], f.y);
    atomicAdd(&sumc[3 * v + 2], f.z);
}

// ---------------- scatter pass 2: mean-dist sums ----------------
__global__ void k_scatter2(const float4* __restrict__ feat, const int* __restrict__ vidx,
                           const float* __restrict__ counts, const float* __restrict__ sumc,
                           float* __restrict__ spd, int n)
{
    int i = blockIdx.x * blockDim.x + threadIdx.x;
    if (i >= n) return;
    int v = vidx[i];
    float safe = fmaxf(counts[v], 1.0f);
    float inv = 1.0f / safe;
    float4 f = feat[i];
    float dx = f.x - sumc[3 * v + 0] * inv;
    float dy = f.y - sumc[3 * v + 1] * inv;
    float dz = f.z - sumc[3 * v + 2] * inv;
    atomicAdd(&spd[v], sqrtf(dx * dx + dy * dy + dz * dz));
}

// ---------------- prex: build x bf16[n][16] + 14x14 moment accumulation ----------------
__global__ __launch_bounds__(256, 2) void k_prex(const float4* __restrict__ feat,
                       const int4* __restrict__ coors,
                       const int* __restrict__ vidx, const float* __restrict__ counts,
                       const float* __restrict__ sumc, const float* __restrict__ spd,
                       unsigned int* __restrict__ x, double* __restrict__ md0, int n)
{
    float mv[105];
#pragma unroll
    for (int e = 0; e < 105; ++e) mv[e] = 0.f;
    int t = threadIdx.x;
    int stride = gridDim.x * blockDim.x;
    for (int i = blockIdx.x * blockDim.x + t; i < n; i += stride) {
        float4 f = feat[i];
        int4 c = coors[i];
        int v = vidx[i];
        float safe = fmaxf(counts[v], 1.0f);
        float inv = 1.0f / safe;
        float vals[14];
        vals[0] = f.x; vals[1] = f.y; vals[2] = f.z; vals[3] = f.w;
        vals[4] = safe / 0.16f;
        vals[5] = spd[v] * inv;
        vals[6] = f.x - sumc[3 * v + 0] * inv;
        vals[7] = f.y - sumc[3 * v + 1] * inv;
        vals[8] = f.z - sumc[3 * v + 2] * inv;
        vals[9]  = f.x - ((float)c.w * VXF + XOFFv);
        vals[10] = f.y - ((float)c.z * VYF + YOFFv);
        vals[11] = f.z - ((float)c.y * VZF + ZOFFv);
        vals[12] = sqrtf(f.x * f.x + f.y * f.y + f.z * f.z);
        vals[13] = 1.0f;
        int idx = 0;
#pragma unroll
        for (int a = 0; a < 14; ++a)
#pragma unroll
            for (int b = a; b < 14; ++b) { mv[idx] = fmaf(vals[a], vals[b], mv[idx]); ++idx; }
        unsigned int row[8];
#pragma unroll
        for (int q = 0; q < 6; ++q) row[q] = pk(vals[2 * q], vals[2 * q + 1]);
        row[6] = pk(vals[12], 0.f);
        row[7] = 0u;
        uint4* dst = (uint4*)(x + (size_t)i * 8);
        dst[0] = make_uint4(row[0], row[1], row[2], row[3]);
        dst[1] = make_uint4(row[4], row[5], row[6], row[7]);
    }
    __shared__ float wacc[4][105];
    int lane = t & 63, wid = t >> 6;
#pragma unroll
    for (int e = 0; e < 105; ++e) {
        float v = mv[e];
        for (int m = 1; m < 64; m <<= 1) v += __shfl_xor(v, m);
        if (lane == 0) wacc[wid][e] = v;
    }
    __syncthreads();
    if (t < 105) {
        double s = (double)wacc[0][t] + (double)wacc[1][t] + (double)wacc[2][t] + (double)wacc[3][t];
        atomicAdd(&md0[t], s);
    }
}

__device__ __forceinline__ int idx14(int a, int b) { // a<=b
    return a * 14 - a * (a - 1) / 2 + (b - a);
}

// ---------------- fin0: BN0 scale/shift from moments ----------------
__global__ void k_fin0(const double* __restrict__ md0, const float* __restrict__ W0,
                       const float* __restrict__ g0, const float* __restrict__ b0,
                       float* __restrict__ sc0, float* __restrict__ sh0, int n)
{
    __shared__ double mom[105];
    int t = threadIdx.x;
    for (int e = t; e < 105; e += 64) mom[e] = md0[e];
    __syncthreads();
    double nn = (double)n;
    double mu[13];
#pragma unroll
    for (int j = 0; j < 13; ++j) mu[j] = mom[idx14(j, 13)] / nn;
    double wc[13];
#pragma unroll
    for (int j = 0; j < 13; ++j) wc[j] = (double)W0[j * 64 + t];
    double meanc = 0.0, var = 0.0;
#pragma unroll
    for (int j = 0; j < 13; ++j) {
        meanc += mu[j] * wc[j];
        for (int k = 0; k < 13; ++k) {
            int a = j < k ? j : k, b = j < k ? k : j;
            double cov = mom[idx14(a, b)] / nn - mu[j] * mu[k];
            var += cov * wc[j] * wc[k];
        }
    }
    float scale = g0[t] * rsqrtf((float)var + EPSF);
    sc0[t] = scale;
    sh0[t] = b0[t] - (float)meanc * scale;
}

// ---------------- scanA ----------------
__global__ __launch_bounds__(1024) void k_scanA(const float* __restrict__ counts,
                                                int* __restrict__ starts, int* __restrict__ bsum)
{
    __shared__ int sdata[1024];
    int t = threadIdx.x;
    int v = blockIdx.x * 1024 + t;
    int c = (int)counts[v];
    sdata[t] = c;
    __syncthreads();
#pragma unroll
    for (int off = 1; off < 1024; off <<= 1) {
        int val = (t >= off) ? sdata[t - off] : 0;
        __syncthreads();
        sdata[t] += val;
        __syncthreads();
    }
    starts[v] = sdata[t] - c; // exclusive
    if (t == 1023) bsum[blockIdx.x] = sdata[t];
}

// ---------------- scanB ----------------
__global__ __launch_bounds__(1024) void k_scanB(int* __restrict__ bsum, int* __restrict__ boff)
{
    __shared__ int sdata[1024];
    int t = threadIdx.x;
    int c = (t < 550) ? bsum[t] : 0;
    sdata[t] = c;
    __syncthreads();
#pragma unroll
    for (int off = 1; off < 1024; off <<= 1) {
        int val = (t >= off) ? sdata[t - off] : 0;
        __syncthreads();
        sdata[t] += val;
        __syncthreads();
    }
    if (t < 550) boff[t] = sdata[t] - c;
}

// ---------------- scanC ----------------
__global__ __launch_bounds__(1024) void k_scanC(int* __restrict__ starts, const int* __restrict__ boff)
{
    int v = blockIdx.x * 1024 + threadIdx.x;
    starts[v] += boff[blockIdx.x];
}

// ---------------- perm (starts becomes INCLUSIVE prefix after this) ----------------
__global__ void k_perm(const int* __restrict__ vidx, int* __restrict__ starts,
                       int* __restrict__ perm, int n)
{
    int i = blockIdx.x * blockDim.x + threadIdx.x;
    if (i >= n) return;
    int pos = atomicAdd(&starts[vidx[i]], 1);
    perm[pos] = i;
}

// ---------------- vmaxv: per-voxel max of p0 + per-point p0 write (bf16) ----------------
__global__ __launch_bounds__(256) void k_vmaxv(const unsigned int* __restrict__ x,
    const float* __restrict__ W0, const float* __restrict__ sc0, const float* __restrict__ sh0,
    const int* __restrict__ startsPost, const int* __restrict__ perm,
    unsigned int* __restrict__ p0, unsigned int* __restrict__ vmaxb, int nvox)
{
    int t = threadIdx.x, lane = t & 63, wid = t >> 6;
    int v = blockIdx.x * 4 + wid;
    if (v >= nvox) return;
    int end = startsPost[v];
    int begin = (v > 0) ? startsPost[v - 1] : 0;
    if (begin == end) return;
    float wcol[13];
#pragma unroll
    for (int k = 0; k < 13; ++k) wcol[k] = W0[k * 64 + lane];
    float sc = sc0[lane], sh = sh0[lane];
    float m = 0.f;
    for (int j = begin; j < end; ++j) {
        int i = perm[j];
        const uint4* xr = (const uint4*)(x + (size_t)i * 8);
        uint4 r0 = xr[0], r1 = xr[1];
        unsigned int rw[8] = {r0.x, r0.y, r0.z, r0.w, r1.x, r1.y, r1.z, r1.w};
        float acc = 0.f;
#pragma unroll
        for (int k = 0; k < 13; ++k) {
            float xv = bf2f((short)((k & 1) ? (rw[k >> 1] >> 16) : (rw[k >> 1] & 0xFFFF)));
            acc = fmaf(xv, wcol[k], acc);
        }
        float pv = fmaxf(fmaf(acc, sc, sh), 0.f);
        float pn = __shfl_xor(pv, 1);
        if ((lane & 1) == 0)
            p0[(size_t)i * 32 + (lane >> 1)] = pk(pv, pn);
        m = fmaxf(m, pv);
    }
    float mn = __shfl_xor(m, 1);
    if ((lane & 1) == 0)
        vmaxb[(size_t)v * 32 + (lane >> 1)] = pk(m, mn);
}

// ---------------- gemm1s: X1=[p0|vmax] @ W1 -> y1 bf16, fused BN1 stats ----------------
#define G1_SW1 0
#define G1_SX  32768
#define G1_ST  65536
#define G1_LDS (65536 + 8192)

__global__ __launch_bounds__(512) void k_gemm1s(const unsigned int* __restrict__ p0,
    const unsigned int* __restrict__ vmaxb, const int* __restrict__ vidx,
    const float* __restrict__ W1, unsigned int* __restrict__ y1,
    double* __restrict__ s1d, double* __restrict__ sq1d, int n, int ntiles)
{
    extern __shared__ char lds[];
    char* sW1 = lds + G1_SW1;
    char* sx  = lds + G1_SX;
    int t = threadIdx.x, lane = t & 63, w = t >> 6;
    int pl = lane & 15, qd = lane >> 4;

    // stage W1 (128x128 f32, [k][c]) -> sW1[c][k] bf16, stride 256B, XOR swizzle
#pragma unroll
    for (int it = 0; it < 8; ++it) {
        int e = (it * 512 + t) * 4;
        float4 wv = *(const float4*)(W1 + e);
        int k = e >> 7, c0 = e & 127;
        float wa[4] = {wv.x, wv.y, wv.z, wv.w};
#pragma unroll
        for (int qq = 0; qq < 4; ++qq) {
            int c = c0 + qq;
            *(short*)(sW1 + c * 256 + ((k * 2) ^ ((c & 7) << 4))) = f2bf(wa[qq]);
        }
    }
    __syncthreads();

    float st_s[8][4], st_q[8][4];
#pragma unroll
    for (int cb = 0; cb < 8; ++cb)
#pragma unroll
        for (int jj = 0; jj < 4; ++jj) { st_s[cb][jj] = 0.f; st_q[cb][jj] = 0.f; }

    unsigned int szr = (unsigned int)(pl & 7) << 4;
    int rb_ = w * 16 + pl;
    for (int tile = blockIdx.x; tile < ntiles; tile += gridDim.x) {
        int base = tile * 128;
        {
            int p = t >> 2, s = t & 3;
            int i = base + p;
            char* rowp = sx + p * 256;
            unsigned int sz = (unsigned int)(p & 7) << 4;
            uint4 d0, d1, d2, d3;
            if (i < n) {
                const uint4* src = (s < 2)
                    ? (const uint4*)(p0 + (size_t)i * 32 + s * 16)
                    : (const uint4*)(vmaxb + (size_t)vidx[i] * 32 + (s - 2) * 16);
                d0 = src[0]; d1 = src[1]; d2 = src[2]; d3 = src[3];
            } else {
                d0 = d1 = d2 = d3 = make_uint4(0u, 0u, 0u, 0u);
            }
            int k2 = s * 64;
            *(uint4*)(rowp + ((k2 +  0) ^ sz)) = d0;
            *(uint4*)(rowp + ((k2 + 16) ^ sz)) = d1;
            *(uint4*)(rowp + ((k2 + 32) ^ sz)) = d2;
            *(uint4*)(rowp + ((k2 + 48) ^ sz)) = d3;
        }
        __syncthreads();
        // MFMA: D[row=channel][col=point]  (a=W-frag, b=x-frag)
        f32x4 acc[8];
#pragma unroll
        for (int cb = 0; cb < 8; ++cb) acc[cb] = (f32x4){0.f, 0.f, 0.f, 0.f};
#pragma unroll
        for (int kc = 0; kc < 4; ++kc) {
            int ko2 = kc * 64 + qd * 16;
            bf16x8 b = *(bf16x8*)(sx + rb_ * 256 + (ko2 ^ szr));
#pragma unroll
            for (int cb = 0; cb < 8; ++cb) {
                int ra_ = cb * 16 + pl;
                bf16x8 a = *(bf16x8*)(sW1 + ra_ * 256 + (ko2 ^ szr));
                acc[cb] = __builtin_amdgcn_mfma_f32_16x16x32_bf16(a, b, acc[cb], 0, 0, 0);
            }
        }
        int pt = base + rb_;
        if (pt < n) {
            char* yrow = (char*)y1 + (size_t)pt * 256 + qd * 8;
#pragma unroll
            for (int cb = 0; cb < 8; ++cb) {
                uint2 o;
                o.x = pk(acc[cb][0], acc[cb][1]);
                o.y = pk(acc[cb][2], acc[cb][3]);
                *(uint2*)(yrow + cb * 32) = o;
#pragma unroll
                for (int jj = 0; jj < 4; ++jj) {
                    float av = acc[cb][jj];
                    st_s[cb][jj] += av;
                    st_q[cb][jj] = fmaf(av, av, st_q[cb][jj]);
                }
            }
        }
        __syncthreads();
    }
    // ---- stats reduction: across pl lanes, then waves, then global double atomics ----
    float* ssum = (float*)(lds + G1_ST);        // [8][128]
    float* ssq  = ssum + 8 * 128;
#pragma unroll
    for (int cb = 0; cb < 8; ++cb)
#pragma unroll
        for (int jj = 0; jj < 4; ++jj) {
            float sv = st_s[cb][jj], qv = st_q[cb][jj];
            sv += __shfl_xor(sv, 1); qv += __shfl_xor(qv, 1);
            sv += __shfl_xor(sv, 2); qv += __shfl_xor(qv, 2);
            sv += __shfl_xor(sv, 4); qv += __shfl_xor(qv, 4);
            sv += __shfl_xor(sv, 8); qv += __shfl_xor(qv, 8);
            if (pl == 0) {
                int ch = cb * 16 + qd * 4 + jj;
                ssum[w * 128 + ch] = sv;
                ssq[w * 128 + ch] = qv;
            }
        }
    __syncthreads();
    if (t < 128) {
        float s = 0.f, q = 0.f;
#pragma unroll
        for (int ww = 0; ww < 8; ++ww) { s += ssum[ww * 128 + t]; q += ssq[ww * 128 + t]; }
        atomicAdd(&s1d[t], (double)s);
        atomicAdd(&sq1d[t], (double)q);
    }
}

__global__ void k_fin1s(const double* __restrict__ s1d, const double* __restrict__ sq1d,
                        const float* __restrict__ g1, const float* __restrict__ b1,
                        float* __restrict__ sc1, float* __restrict__ sh1, int n)
{
    int c = threadIdx.x;
    double mean = s1d[c] / (double)n;
    double var = sq1d[c] / (double)n - mean * mean;
    float scale = g1[c] * rsqrtf((float)var + EPSF);
    sc1[c] = scale;
    sh1[c] = b1[c] - (float)mean * scale;
}

// ---------------- fused2: BN+ReLU(y1) |fsp -> @ Ws + bs -> ReLU -> out ----------------
#define F2_SWS 0
#define F2_SX  49152
#define F2_SCL (49152 + 24576)
#define F2_LDS (F2_SCL + 1536)

__global__ __launch_bounds__(256) void k_fused2(const uint4* __restrict__ y1,
    const unsigned int* __restrict__ x,
    const float* __restrict__ Wsp, const float* __restrict__ bsp,
    const float* __restrict__ sc1, const float* __restrict__ sh1,
    float* __restrict__ out, int n, int ntiles)
{
    extern __shared__ char lds[];
    char* sWs = lds + F2_SWS;
    char* sx  = lds + F2_SX;
    float* ssc = (float*)(lds + F2_SCL);
    float* ssh = ssc + 128;
    float* sbs = ssh + 128;
    int t = threadIdx.x, lane = t & 63, w = t >> 6;
    int pl = lane & 15, qd = lane >> 4;

    for (int it = 0; it < 17; ++it) {
        int e = (it * 256 + t) * 4;
        if (e < 16640) {
            float4 wv = *(const float4*)(Wsp + e);
            int k = e >> 7, c0 = e & 127;
            float wa[4] = {wv.x, wv.y, wv.z, wv.w};
#pragma unroll
            for (int qq = 0; qq < 4; ++qq) {
                int c = c0 + qq;
                *(short*)(sWs + c * 384 + ((k * 2) ^ ((c & 7) << 4))) = f2bf(wa[qq]);
            }
        }
    }
    for (int e = t; e < 128 * 15; e += 256) {
        int r = e / 15, qq = e - r * 15;
        int k2 = 260 + 4 * qq;
        *(unsigned int*)(sWs + r * 384 + (k2 ^ ((r & 7) << 4))) = 0u;
    }
    for (int e = t; e < 64 * 15; e += 256) {
        int r = e / 15, qq = e - r * 15;
        int k2 = 260 + 4 * qq;
        *(unsigned int*)(sx + r * 384 + (k2 ^ ((r & 7) << 4))) = 0u;
    }
    if (t < 128) { ssc[t] = sc1[t]; ssh[t] = sh1[t]; sbs[t] = bsp[t]; }
    __syncthreads();

    unsigned int szr = (unsigned int)(pl & 7) << 4;
    int rb_ = w * 16 + pl;
    for (int tile = blockIdx.x; tile < ntiles; tile += gridDim.x) {
        int base = tile * 64;
        {
            int p = t >> 2, s = t & 3;
            int i = base + p;
            char* rowp = sx + p * 384;
            unsigned int sz = (unsigned int)(p & 7) << 4;
            unsigned int ow[16];
            if (i < n) {
                const uint4* src = (const uint4*)((const char*)y1 + (size_t)i * 256 + s * 64);
                uint4 d0 = src[0], d1 = src[1], d2 = src[2], d3 = src[3];
                unsigned int iw[16] = {d0.x, d0.y, d0.z, d0.w, d1.x, d1.y, d1.z, d1.w,
                                       d2.x, d2.y, d2.z, d2.w, d3.x, d3.y, d3.z, d3.w};
#pragma unroll
                for (int qq = 0; qq < 16; ++qq) {
                    int c = s * 32 + 2 * qq;
                    float a = fmaxf(fmaf(bf2f((short)(iw[qq] & 0xFFFF)), ssc[c], ssh[c]), 0.f);
                    float b = fmaxf(fmaf(bf2f((short)(iw[qq] >> 16)), ssc[c + 1], ssh[c + 1]), 0.f);
                    ow[qq] = pk(a, b);
                }
            } else {
#pragma unroll
                for (int qq = 0; qq < 16; ++qq) ow[qq] = 0u;
            }
            int k2 = s * 64;
#pragma unroll
            for (int qq = 0; qq < 4; ++qq)
                *(uint4*)(rowp + ((k2 + 16 * qq) ^ sz)) =
                    make_uint4(ow[4 * qq], ow[4 * qq + 1], ow[4 * qq + 2], ow[4 * qq + 3]);
        }
        if (t < 64) {
            int i = base + t; if (i >= n) i = n - 1;
            unsigned int fs = x[(size_t)i * 8 + 2];
            *(unsigned int*)(sx + t * 384 + (256 ^ ((t & 7) << 4))) = fs;
        }
        __syncthreads();
        f32x4 acc[8];
#pragma unroll
        for (int cb = 0; cb < 8; ++cb) acc[cb] = (f32x4){0.f, 0.f, 0.f, 0.f};
#pragma unroll
        for (int kc = 0; kc < 5; ++kc) {
            int ko2 = kc * 64 + qd * 16;
            bf16x8 b = *(bf16x8*)(sx + rb_ * 384 + (ko2 ^ szr));
#pragma unroll
            for (int cb = 0; cb < 8; ++cb) {
                int ra_ = cb * 16 + pl;
                bf16x8 a = *(bf16x8*)(sWs + ra_ * 384 + (ko2 ^ szr));
                acc[cb] = __builtin_amdgcn_mfma_f32_16x16x32_bf16(a, b, acc[cb], 0, 0, 0);
            }
        }
        int pt = base + rb_;
        if (pt < n) {
            float* orow = out + (size_t)pt * 128 + qd * 4;
#pragma unroll
            for (int cb = 0; cb < 8; ++cb) {
                float4 bb = *(float4*)(sbs + cb * 16 + qd * 4);
                float4 o;
                o.x = fmaxf(acc[cb][0] + bb.x, 0.f);
                o.y = fmaxf(acc[cb][1] + bb.y, 0.f);
                o.z = fmaxf(acc[cb][2] + bb.z, 0.f);
                o.w = fmaxf(acc[cb][3] + bb.w, 0.f);
                *(float4*)(orow + cb * 16) = o;
            }
        }
        __syncthreads();
    }
}

extern "C" void kernel_launch(void* const* d_in, const int* in_sizes, int n_in,
                              void* d_out, int out_size, void* d_ws, size_t ws_size,
                              hipStream_t stream)
{
    const float* feat = (const float*)d_in[0];
    const int*   coor = (const int*)d_in[1];
    const float* W0   = (const float*)d_in[2];
    const float* g0   = (const float*)d_in[3];
    const float* b0   = (const float*)d_in[4];
    const float* W1   = (const float*)d_in[5];
    const float* g1   = (const float*)d_in[6];
    const float* b1   = (const float*)d_in[7];
    const float* Wsp  = (const float*)d_in[8];
    const float* bsp  = (const float*)d_in[9];
    float* outp = (float*)d_out;

    int n = in_sizes[0] / 4;
    size_t npad = ((size_t)n + 127) & ~127ULL;

    char* ws = (char*)d_ws;
    size_t off = 0;
    auto alloc = [&](size_t bytes) { char* p = ws + off; off = (off + bytes + 255) & ~255ULL; return p; };
    int*          vidx   = (int*)alloc(npad * 4);
    float*        counts = (float*)alloc((size_t)CANVASv * 4);
    float*        sumc   = (float*)alloc((size_t)CANVASv * 12);
    float*        spd    = (float*)alloc((size_t)CANVASv * 4);
    unsigned int* x      = (unsigned int*)alloc(npad * 32);
    unsigned int* p0     = (unsigned int*)alloc(npad * 128);
    unsigned int* vmaxb  = (unsigned int*)alloc((size_t)CANVASv * 128);
    unsigned int* y1     = (unsigned int*)alloc(npad * 256);
    int*          starts = (int*)alloc((size_t)CANVASv * 4);
    int*          perm   = (int*)alloc(npad * 4);
    int*          bsum   = (int*)alloc(1024 * 4);
    int*          boff   = (int*)alloc(1024 * 4);
    double*       md0    = (double*)alloc(105 * 8 + 256 * 8);
    double*       s1d    = (double*)((char*)md0 + 105 * 8);
    double*       sq1d   = s1d + 128;
    float*        sc0    = (float*)alloc(64 * 4);
    float*        sh0    = (float*)alloc(64 * 4);
    float*        sc1    = (float*)alloc(128 * 4);
    float*        sh1    = (float*)alloc(128 * 4);
    if (off > ws_size) return;

    hipMemsetAsync(counts, 0, (size_t)CANVASv * 4 * 5, stream);
    hipMemsetAsync(md0, 0, 105 * 8 + 256 * 8, stream);

    int blocksN = (n + 255) / 256;
    k_scatter1<<<blocksN, 256, 0, stream>>>((const float4*)feat, (const int4*)coor, vidx, counts, sumc, n);
    k_scatter2<<<blocksN, 256, 0, stream>>>((const float4*)feat, vidx, counts, sumc, spd, n);
    k_prex<<<512, 256, 0, stream>>>((const float4*)feat, (const int4*)coor, vidx, counts, sumc, spd, x, md0, n);
    k_fin0<<<1, 64, 0, stream>>>(md0, W0, g0, b0, sc0, sh0, n);

    // counting sort by voxel
    k_scanA<<<CANVASv / 1024, 1024, 0, stream>>>(counts, starts, bsum);
    k_scanB<<<1, 1024, 0, stream>>>(bsum, boff);
    k_scanC<<<CANVASv / 1024, 1024, 0, stream>>>(starts, boff);
    k_perm<<<blocksN, 256, 0, stream>>>(vidx, starts, perm, n);
    // per-voxel max + per-point p0 (starts is now inclusive prefix)
    k_vmaxv<<<(CANVASv + 3) / 4, 256, 0, stream>>>(x, W0, sc0, sh0, starts, perm, p0, vmaxb, CANVASv);

    int ntiles1 = (n + 127) / 128;
    hipFuncSetAttribute((const void*)k_gemm1s, hipFuncAttributeMaxDynamicSharedMemorySize, G1_LDS);
    k_gemm1s<<<512, 512, G1_LDS, stream>>>(p0, vmaxb, vidx, W1, y1, s1d, sq1d, n, ntiles1);

    k_fin1s<<<1, 128, 0, stream>>>(s1d, sq1d, g1, b1, sc1, sh1, n);

    int ntiles2 = (n + 63) / 64;
    hipFuncSetAttribute((const void*)k_fused2, hipFuncAttributeMaxDynamicSharedMemorySize, F2_LDS);
    k_fused2<<<512, 256, F2_LDS, stream>>>((const uint4*)y1, x, Wsp, bsp, sc1, sh1, outp, n, ntiles2);
}

// Round 6
// 573.263 us; speedup vs baseline: 6.0680x; 1.0417x over previous
//
#include <hip/hip_runtime.h>
#include <hip/hip_bf16.h>

#define NZv 1
#define NYv 400
#define NXv 352
#define Bv 4
#define CANVASv (Bv * NZv * NYv * NXv) /* 563200 = 550 * 1024 */
#define EPSF 0.001f
#define VXF 0.2f
#define VYF 0.2f
#define VZF 4.0f
#define XOFFv 0.1f
#define YOFFv -39.9f
#define ZOFFv -1.0f

typedef __attribute__((ext_vector_type(8))) short bf16x8;
typedef __attribute__((ext_vector_type(4))) float f32x4;

__device__ __forceinline__ short f2bf(float f) {
    union { __hip_bfloat16 h; short s; } u;
    u.h = __float2bfloat16(f);
    return u.s;
}
__device__ __forceinline__ float bf2f(short s) {
    return __uint_as_float(((unsigned int)(unsigned short)s) << 16);
}
__device__ __forceinline__ unsigned int pk(float a, float b) {
    return (unsigned int)(unsigned short)f2bf(a) | ((unsigned int)(unsigned short)f2bf(b) << 16);
}

// compile-time index tables for the 105 upper-triangle moments (a<=b, a-major)
struct MomTab { signed char a[105]; signed char b[105]; };
constexpr MomTab make_momtab() {
    MomTab m{};
    int idx = 0;
    for (int a = 0; a < 14; ++a)
        for (int b = a; b < 14; ++b) { m.a[idx] = (signed char)a; m.b[idx] = (signed char)b; ++idx; }
    return m;
}
constexpr MomTab MT = make_momtab();

// ---------------- scatter pass 1: count + coord sums ----------------
__global__ void k_scatter1(const float4* __restrict__ feat, const int4* __restrict__ coors,
                           int* __restrict__ vidx, float* __restrict__ counts,
                           float* __restrict__ sumc, int n)
{
    int i = blockIdx.x * blockDim.x + threadIdx.x;
    if (i >= n) return;
    int4 c = coors[i];
    int v = ((c.x * NZv + c.y) * NYv + c.z) * NXv + c.w;
    vidx[i] = v;
    float4 f = feat[i];
    atomicAdd(&counts[v], 1.0f);
    atomicAdd(&sumc[3 * v + 0], f.x);
    atomicAdd(&sumc[3 * v + 1], f.y);
    atomicAdd(&sumc[3 * v + 2], f.z);
}

// ---------------- scatter pass 2: mean-dist sums ----------------
__global__ void k_scatter2(const float4* __restrict__ feat, const int* __restrict__ vidx,
                           const float* __restrict__ counts, const float* __restrict__ sumc,
                           float* __restrict__ spd, int n)
{
    int i = blockIdx.x * blockDim.x + threadIdx.x;
    if (i >= n) return;
    int v = vidx[i];
    float safe = fmaxf(counts[v], 1.0f);
    float inv = 1.0f / safe;
    float4 f = feat[i];
    float dx = f.x - sumc[3 * v + 0] * inv;
    float dy = f.y - sumc[3 * v + 1] * inv;
    float dz = f.z - sumc[3 * v + 2] * inv;
    atomicAdd(&spd[v], sqrtf(dx * dx + dy * dy + dz * dz));
}

// ---------------- prex: build x bf16[n][16] (streaming, no moments) ----------------
__global__ __launch_bounds__(256) void k_prex(const float4* __restrict__ feat,
                       const int4* __restrict__ coors,
                       const int* __restrict__ vidx, const float* __restrict__ counts,
                       const float* __restrict__ sumc, const float* __restrict__ spd,
                       unsigned int* __restrict__ x, int n)
{
    int t = threadIdx.x;
    int stride = gridDim.x * blockDim.x;
    for (int i = blockIdx.x * blockDim.x + t; i < n; i += stride) {
        float4 f = feat[i];
        int4 c = coors[i];
        int v = vidx[i];
        float safe = fmaxf(counts[v], 1.0f);
        float inv = 1.0f / safe;
        float vals[13];
        vals[0] = f.x; vals[1] = f.y; vals[2] = f.z; vals[3] = f.w;
        vals[4] = safe / 0.16f;
        vals[5] = spd[v] * inv;
        vals[6] = f.x - sumc[3 * v + 0] * inv;
        vals[7] = f.y - sumc[3 * v + 1] * inv;
        vals[8] = f.z - sumc[3 * v + 2] * inv;
        vals[9]  = f.x - ((float)c.w * VXF + XOFFv);
        vals[10] = f.y - ((float)c.z * VYF + YOFFv);
        vals[11] = f.z - ((float)c.y * VZF + ZOFFv);
        vals[12] = sqrtf(f.x * f.x + f.y * f.y + f.z * f.z);
        unsigned int row[8];
#pragma unroll
        for (int q = 0; q < 6; ++q) row[q] = pk(vals[2 * q], vals[2 * q + 1]);
        row[6] = pk(vals[12], 0.f);
        row[7] = 0u;
        uint4* dst = (uint4*)(x + (size_t)i * 8);
        dst[0] = make_uint4(row[0], row[1], row[2], row[3]);
        dst[1] = make_uint4(row[4], row[5], row[6], row[7]);
    }
}

// ---------------- mom: 14x14 moments from bf16 x rows, all-static indexing ----------------
__global__ __launch_bounds__(256, 1) void k_mom(const uint4* __restrict__ x4,
                                                double* __restrict__ md0, int n)
{
    float acc[105];
#pragma unroll
    for (int e = 0; e < 105; ++e) acc[e] = 0.f;
    int t = threadIdx.x;
    int stride = gridDim.x * blockDim.x;
    for (int i = blockIdx.x * blockDim.x + t; i < n; i += stride) {
        uint4 r0 = x4[2 * (size_t)i];
        uint4 r1 = x4[2 * (size_t)i + 1];
        unsigned int rw[7] = {r0.x, r0.y, r0.z, r0.w, r1.x, r1.y, r1.z};
        float vals[14];
#pragma unroll
        for (int k = 0; k < 13; ++k)
            vals[k] = bf2f((short)((k & 1) ? (rw[k >> 1] >> 16) : (rw[k >> 1] & 0xFFFF)));
        vals[13] = 1.0f;
#pragma unroll
        for (int e = 0; e < 105; ++e)
            acc[e] = fmaf(vals[MT.a[e]], vals[MT.b[e]], acc[e]);
    }
    __shared__ float wacc[4][105];
    int lane = t & 63, wid = t >> 6;
#pragma unroll
    for (int e = 0; e < 105; ++e) {
        float v = acc[e];
        v += __shfl_xor(v, 1);
        v += __shfl_xor(v, 2);
        v += __shfl_xor(v, 4);
        v += __shfl_xor(v, 8);
        v += __shfl_xor(v, 16);
        v += __shfl_xor(v, 32);
        if (lane == 0) wacc[wid][e] = v;
    }
    __syncthreads();
    if (t < 105) {
        double s = (double)wacc[0][t] + (double)wacc[1][t] + (double)wacc[2][t] + (double)wacc[3][t];
        atomicAdd(&md0[t], s);
    }
}

__device__ __forceinline__ int idx14(int a, int b) { // a<=b
    return a * 14 - a * (a - 1) / 2 + (b - a);
}

// ---------------- fin0: BN0 scale/shift from moments ----------------
__global__ void k_fin0(const double* __restrict__ md0, const float* __restrict__ W0,
                       const float* __restrict__ g0, const float* __restrict__ b0,
                       float* __restrict__ sc0, float* __restrict__ sh0, int n)
{
    __shared__ double mom[105];
    int t = threadIdx.x;
    for (int e = t; e < 105; e += 64) mom[e] = md0[e];
    __syncthreads();
    double nn = (double)n;
    double mu[13];
#pragma unroll
    for (int j = 0; j < 13; ++j) mu[j] = mom[idx14(j, 13)] / nn;
    double wc[13];
#pragma unroll
    for (int j = 0; j < 13; ++j) wc[j] = (double)W0[j * 64 + t];
    double meanc = 0.0, var = 0.0;
#pragma unroll
    for (int j = 0; j < 13; ++j) {
        meanc += mu[j] * wc[j];
        for (int k = 0; k < 13; ++k) {
            int a = j < k ? j : k, b = j < k ? k : j;
            double cov = mom[idx14(a, b)] / nn - mu[j] * mu[k];
            var += cov * wc[j] * wc[k];
        }
    }
    float scale = g0[t] * rsqrtf((float)var + EPSF);
    sc0[t] = scale;
    sh0[t] = b0[t] - (float)meanc * scale;
}

// ---------------- scanA ----------------
__global__ __launch_bounds__(1024) void k_scanA(const float* __restrict__ counts,
                                                int* __restrict__ starts, int* __restrict__ bsum)
{
    __shared__ int sdata[1024];
    int t = threadIdx.x;
    int v = blockIdx.x * 1024 + t;
    int c = (int)counts[v];
    sdata[t] = c;
    __syncthreads();
#pragma unroll
    for (int off = 1; off < 1024; off <<= 1) {
        int val = (t >= off) ? sdata[t - off] : 0;
        __syncthreads();
        sdata[t] += val;
        __syncthreads();
    }
    starts[v] = sdata[t] - c; // exclusive
    if (t == 1023) bsum[blockIdx.x] = sdata[t];
}

// ---------------- scanB ----------------
__global__ __launch_bounds__(1024) void k_scanB(int* __restrict__ bsum, int* __restrict__ boff)
{
    __shared__ int sdata[1024];
    int t = threadIdx.x;
    int c = (t < 550) ? bsum[t] : 0;
    sdata[t] = c;
    __syncthreads();
#pragma unroll
    for (int off = 1; off < 1024; off <<= 1) {
        int val = (t >= off) ? sdata[t - off] : 0;
        __syncthreads();
        sdata[t] += val;
        __syncthreads();
    }
    if (t < 550) boff[t] = sdata[t] - c;
}

// ---------------- scanC ----------------
__global__ __launch_bounds__(1024) void k_scanC(int* __restrict__ starts, const int* __restrict__ boff)
{
    int v = blockIdx.x * 1024 + threadIdx.x;
    starts[v] += boff[blockIdx.x];
}

// ---------------- perm (starts becomes INCLUSIVE prefix after this) ----------------
__global__ void k_perm(const int* __restrict__ vidx, int* __restrict__ starts,
                       int* __restrict__ perm, int n)
{
    int i = blockIdx.x * blockDim.x + threadIdx.x;
    if (i >= n) return;
    int pos = atomicAdd(&starts[vidx[i]], 1);
    perm[pos] = i;
}

// ---------------- vmaxv: per-voxel max of p0 + per-point p0 write (bf16) ----------------
__global__ __launch_bounds__(256) void k_vmaxv(const unsigned int* __restrict__ x,
    const float* __restrict__ W0, const float* __restrict__ sc0, const float* __restrict__ sh0,
    const int* __restrict__ startsPost, const int* __restrict__ perm,
    unsigned int* __restrict__ p0, unsigned int* __restrict__ vmaxb, int nvox)
{
    int t = threadIdx.x, lane = t & 63, wid = t >> 6;
    int v = blockIdx.x * 4 + wid;
    if (v >= nvox) return;
    int end = startsPost[v];
    int begin = (v > 0) ? startsPost[v - 1] : 0;
    if (begin == end) return;
    float wcol[13];
#pragma unroll
    for (int k = 0; k < 13; ++k) wcol[k] = W0[k * 64 + lane];
    float sc = sc0[lane], sh = sh0[lane];
    float m = 0.f;
    for (int j = begin; j < end; ++j) {
        int i = perm[j];
        const uint4* xr = (const uint4*)(x + (size_t)i * 8);
        uint4 r0 = xr[0], r1 = xr[1];
        unsigned int rw[8] = {r0.x, r0.y, r0.z, r0.w, r1.x, r1.y, r1.z, r1.w};
        float acc = 0.f;
#pragma unroll
        for (int k = 0; k < 13; ++k) {
            float xv = bf2f((short)((k & 1) ? (rw[k >> 1] >> 16) : (rw[k >> 1] & 0xFFFF)));
            acc = fmaf(xv, wcol[k], acc);
        }
        float pv = fmaxf(fmaf(acc, sc, sh), 0.f);
        float pn = __shfl_xor(pv, 1);
        if ((lane & 1) == 0)
            p0[(size_t)i * 32 + (lane >> 1)] = pk(pv, pn);
        m = fmaxf(m, pv);
    }
    float mn = __shfl_xor(m, 1);
    if ((lane & 1) == 0)
        vmaxb[(size_t)v * 32 + (lane >> 1)] = pk(m, mn);
}

// ---------------- gemm1s: X1=[p0|vmax] @ W1 -> y1 bf16, fused BN1 stats ----------------
#define G1_SW1 0
#define G1_SX  32768
#define G1_ST  65536
#define G1_LDS (65536 + 8192)

__global__ __launch_bounds__(512) void k_gemm1s(const unsigned int* __restrict__ p0,
    const unsigned int* __restrict__ vmaxb, const int* __restrict__ vidx,
    const float* __restrict__ W1, unsigned int* __restrict__ y1,
    double* __restrict__ s1d, double* __restrict__ sq1d, int n, int ntiles)
{
    extern __shared__ char lds[];
    char* sW1 = lds + G1_SW1;
    char* sx  = lds + G1_SX;
    int t = threadIdx.x, lane = t & 63, w = t >> 6;
    int pl = lane & 15, qd = lane >> 4;

    // stage W1 (128x128 f32, [k][c]) -> sW1[c][k] bf16, stride 256B, XOR swizzle
#pragma unroll
    for (int it = 0; it < 8; ++it) {
        int e = (it * 512 + t) * 4;
        float4 wv = *(const float4*)(W1 + e);
        int k = e >> 7, c0 = e & 127;
        float wa[4] = {wv.x, wv.y, wv.z, wv.w};
#pragma unroll
        for (int qq = 0; qq < 4; ++qq) {
            int c = c0 + qq;
            *(short*)(sW1 + c * 256 + ((k * 2) ^ ((c & 7) << 4))) = f2bf(wa[qq]);
        }
    }
    __syncthreads();

    float st_s[8][4], st_q[8][4];
#pragma unroll
    for (int cb = 0; cb < 8; ++cb)
#pragma unroll
        for (int jj = 0; jj < 4; ++jj) { st_s[cb][jj] = 0.f; st_q[cb][jj] = 0.f; }

    unsigned int szr = (unsigned int)(pl & 7) << 4;
    int rb_ = w * 16 + pl;
    for (int tile = blockIdx.x; tile < ntiles; tile += gridDim.x) {
        int base = tile * 128;
        {
            int p = t >> 2, s = t & 3;
            int i = base + p;
            char* rowp = sx + p * 256;
            unsigned int sz = (unsigned int)(p & 7) << 4;
            uint4 d0, d1, d2, d3;
            if (i < n) {
                const uint4* src = (s < 2)
                    ? (const uint4*)(p0 + (size_t)i * 32 + s * 16)
                    : (const uint4*)(vmaxb + (size_t)vidx[i] * 32 + (s - 2) * 16);
                d0 = src[0]; d1 = src[1]; d2 = src[2]; d3 = src[3];
            } else {
                d0 = d1 = d2 = d3 = make_uint4(0u, 0u, 0u, 0u);
            }
            int k2 = s * 64;
            *(uint4*)(rowp + ((k2 +  0) ^ sz)) = d0;
            *(uint4*)(rowp + ((k2 + 16) ^ sz)) = d1;
            *(uint4*)(rowp + ((k2 + 32) ^ sz)) = d2;
            *(uint4*)(rowp + ((k2 + 48) ^ sz)) = d3;
        }
        __syncthreads();
        // MFMA: D[row=channel][col=point]  (a=W-frag, b=x-frag)
        f32x4 acc[8];
#pragma unroll
        for (int cb = 0; cb < 8; ++cb) acc[cb] = (f32x4){0.f, 0.f, 0.f, 0.f};
#pragma unroll
        for (int kc = 0; kc < 4; ++kc) {
            int ko2 = kc * 64 + qd * 16;
            bf16x8 b = *(bf16x8*)(sx + rb_ * 256 + (ko2 ^ szr));
#pragma unroll
            for (int cb = 0; cb < 8; ++cb) {
                int ra_ = cb * 16 + pl;
                bf16x8 a = *(bf16x8*)(sW1 + ra_ * 256 + (ko2 ^ szr));
                acc[cb] = __builtin_amdgcn_mfma_f32_16x16x32_bf16(a, b, acc[cb], 0, 0, 0);
            }
        }
        int pt = base + rb_;
        if (pt < n) {
            char* yrow = (char*)y1 + (size_t)pt * 256 + qd * 8;
#pragma unroll
            for (int cb = 0; cb < 8; ++cb) {
                uint2 o;
                o.x = pk(acc[cb][0], acc[cb][1]);
                o.y = pk(acc[cb][2], acc[cb][3]);
                *(uint2*)(yrow + cb * 32) = o;
#pragma unroll
                for (int jj = 0; jj < 4; ++jj) {
                    float av = acc[cb][jj];
                    st_s[cb][jj] += av;
                    st_q[cb][jj] = fmaf(av, av, st_q[cb][jj]);
                }
            }
        }
        __syncthreads();
    }
    // ---- stats reduction: across pl lanes, then waves, then global double atomics ----
    float* ssum = (float*)(lds + G1_ST);        // [8][128]
    float* ssq  = ssum + 8 * 128;
#pragma unroll
    for (int cb = 0; cb < 8; ++cb)
#pragma unroll
        for (int jj = 0; jj < 4; ++jj) {
            float sv = st_s[cb][jj], qv = st_q[cb][jj];
            sv += __shfl_xor(sv, 1); qv += __shfl_xor(qv, 1);
            sv += __shfl_xor(sv, 2); qv += __shfl_xor(qv, 2);
            sv += __shfl_xor(sv, 4); qv += __shfl_xor(qv, 4);
            sv += __shfl_xor(sv, 8); qv += __shfl_xor(qv, 8);
            if (pl == 0) {
                int ch = cb * 16 + qd * 4 + jj;
                ssum[w * 128 + ch] = sv;
                ssq[w * 128 + ch] = qv;
            }
        }
    __syncthreads();
    if (t < 128) {
        float s = 0.f, q = 0.f;
#pragma unroll
        for (int ww = 0; ww < 8; ++ww) { s += ssum[ww * 128 + t]; q += ssq[ww * 128 + t]; }
        atomicAdd(&s1d[t], (double)s);
        atomicAdd(&sq1d[t], (double)q);
    }
}

__global__ void k_fin1s(const double* __restrict__ s1d, const double* __restrict__ sq1d,
                        const float* __restrict__ g1, const float* __restrict__ b1,
                        float* __restrict__ sc1, float* __restrict__ sh1, int n)
{
    int c = threadIdx.x;
    double mean = s1d[c] / (double)n;
    double var = sq1d[c] / (double)n - mean * mean;
    float scale = g1[c] * rsqrtf((float)var + EPSF);
    sc1[c] = scale;
    sh1[c] = b1[c] - (float)mean * scale;
}

// ---------------- fused2: BN+ReLU(y1) |fsp -> @ Ws + bs -> ReLU -> out ----------------
#define F2_SWS 0
#define F2_SX  49152
#define F2_SCL (49152 + 24576)
#define F2_LDS (F2_SCL + 1536)

__global__ __launch_bounds__(256) void k_fused2(const uint4* __restrict__ y1,
    const unsigned int* __restrict__ x,
    const float* __restrict__ Wsp, const float* __restrict__ bsp,
    const float* __restrict__ sc1, const float* __restrict__ sh1,
    float* __restrict__ out, int n, int ntiles)
{
    extern __shared__ char lds[];
    char* sWs = lds + F2_SWS;
    char* sx  = lds + F2_SX;
    float* ssc = (float*)(lds + F2_SCL);
    float* ssh = ssc + 128;
    float* sbs = ssh + 128;
    int t = threadIdx.x, lane = t & 63, w = t >> 6;
    int pl = lane & 15, qd = lane >> 4;

    for (int it = 0; it < 17; ++it) {
        int e = (it * 256 + t) * 4;
        if (e < 16640) {
            float4 wv = *(const float4*)(Wsp + e);
            int k = e >> 7, c0 = e & 127;
            float wa[4] = {wv.x, wv.y, wv.z, wv.w};
#pragma unroll
            for (int qq = 0; qq < 4; ++qq) {
                int c = c0 + qq;
                *(short*)(sWs + c * 384 + ((k * 2) ^ ((c & 7) << 4))) = f2bf(wa[qq]);
            }
        }
    }
    for (int e = t; e < 128 * 15; e += 256) {
        int r = e / 15, qq = e - r * 15;
        int k2 = 260 + 4 * qq;
        *(unsigned int*)(sWs + r * 384 + (k2 ^ ((r & 7) << 4))) = 0u;
    }
    for (int e = t; e < 64 * 15; e += 256) {
        int r = e / 15, qq = e - r * 15;
        int k2 = 260 + 4 * qq;
        *(unsigned int*)(sx + r * 384 + (k2 ^ ((r & 7) << 4))) = 0u;
    }
    if (t < 128) { ssc[t] = sc1[t]; ssh[t] = sh1[t]; sbs[t] = bsp[t]; }
    __syncthreads();

    unsigned int szr = (unsigned int)(pl & 7) << 4;
    int rb_ = w * 16 + pl;
    for (int tile = blockIdx.x; tile < ntiles; tile += gridDim.x) {
        int base = tile * 64;
        {
            int p = t >> 2, s = t & 3;
            int i = base + p;
            char* rowp = sx + p * 384;
            unsigned int sz = (unsigned int)(p & 7) << 4;
            unsigned int ow[16];
            if (i < n) {
                const uint4* src = (const uint4*)((const char*)y1 + (size_t)i * 256 + s * 64);
                uint4 d0 = src[0], d1 = src[1], d2 = src[2], d3 = src[3];
                unsigned int iw[16] = {d0.x, d0.y, d0.z, d0.w, d1.x, d1.y, d1.z, d1.w,
                                       d2.x, d2.y, d2.z, d2.w, d3.x, d3.y, d3.z, d3.w};
#pragma unroll
                for (int qq = 0; qq < 16; ++qq) {
                    int c = s * 32 + 2 * qq;
                    float a = fmaxf(fmaf(bf2f((short)(iw[qq] & 0xFFFF)), ssc[c], ssh[c]), 0.f);
                    float b = fmaxf(fmaf(bf2f((short)(iw[qq] >> 16)), ssc[c + 1], ssh[c + 1]), 0.f);
                    ow[qq] = pk(a, b);
                }
            } else {
#pragma unroll
                for (int qq = 0; qq < 16; ++qq) ow[qq] = 0u;
            }
            int k2 = s * 64;
#pragma unroll
            for (int qq = 0; qq < 4; ++qq)
                *(uint4*)(rowp + ((k2 + 16 * qq) ^ sz)) =
                    make_uint4(ow[4 * qq], ow[4 * qq + 1], ow[4 * qq + 2], ow[4 * qq + 3]);
        }
        if (t < 64) {
            int i = base + t; if (i >= n) i = n - 1;
            unsigned int fs = x[(size_t)i * 8 + 2];
            *(unsigned int*)(sx + t * 384 + (256 ^ ((t & 7) << 4))) = fs;
        }
        __syncthreads();
        f32x4 acc[8];
#pragma unroll
        for (int cb = 0; cb < 8; ++cb) acc[cb] = (f32x4){0.f, 0.f, 0.f, 0.f};
#pragma unroll
        for (int kc = 0; kc < 5; ++kc) {
            int ko2 = kc * 64 + qd * 16;
            bf16x8 b = *(bf16x8*)(sx + rb_ * 384 + (ko2 ^ szr));
#pragma unroll
            for (int cb = 0; cb < 8; ++cb) {
                int ra_ = cb * 16 + pl;
                bf16x8 a = *(bf16x8*)(sWs + ra_ * 384 + (ko2 ^ szr));
                acc[cb] = __builtin_amdgcn_mfma_f32_16x16x32_bf16(a, b, acc[cb], 0, 0, 0);
            }
        }
        int pt = base + rb_;
        if (pt < n) {
            float* orow = out + (size_t)pt * 128 + qd * 4;
#pragma unroll
            for (int cb = 0; cb < 8; ++cb) {
                float4 bb = *(float4*)(sbs + cb * 16 + qd * 4);
                float4 o;
                o.x = fmaxf(acc[cb][0] + bb.x, 0.f);
                o.y = fmaxf(acc[cb][1] + bb.y, 0.f);
                o.z = fmaxf(acc[cb][2] + bb.z, 0.f);
                o.w = fmaxf(acc[cb][3] + bb.w, 0.f);
                *(float4*)(orow + cb * 16) = o;
            }
        }
        __syncthreads();
    }
}

extern "C" void kernel_launch(void* const* d_in, const int* in_sizes, int n_in,
                              void* d_out, int out_size, void* d_ws, size_t ws_size,
                              hipStream_t stream)
{
    const float* feat = (const float*)d_in[0];
    const int*   coor = (const int*)d_in[1];
    const float* W0   = (const float*)d_in[2];
    const float* g0   = (const float*)d_in[3];
    const float* b0   = (const float*)d_in[4];
    const float* W1   = (const float*)d_in[5];
    const float* g1   = (const float*)d_in[6];
    const float* b1   = (const float*)d_in[7];
    const float* Wsp  = (const float*)d_in[8];
    const float* bsp  = (const float*)d_in[9];
    float* outp = (float*)d_out;

    int n = in_sizes[0] / 4;
    size_t npad = ((size_t)n + 127) & ~127ULL;

    char* ws = (char*)d_ws;
    size_t off = 0;
    auto alloc = [&](size_t bytes) { char* p = ws + off; off = (off + bytes + 255) & ~255ULL; return p; };
    int*          vidx   = (int*)alloc(npad * 4);
    float*        counts = (float*)alloc((size_t)CANVASv * 4);
    float*        sumc   = (float*)alloc((size_t)CANVASv * 12);
    float*        spd    = (float*)alloc((size_t)CANVASv * 4);
    unsigned int* x      = (unsigned int*)alloc(npad * 32);
    unsigned int* p0     = (unsigned int*)alloc(npad * 128);
    unsigned int* vmaxb  = (unsigned int*)alloc((size_t)CANVASv * 128);
    unsigned int* y1     = (unsigned int*)alloc(npad * 256);
    int*          starts = (int*)alloc((size_t)CANVASv * 4);
    int*          perm   = (int*)alloc(npad * 4);
    int*          bsum   = (int*)alloc(1024 * 4);
    int*          boff   = (int*)alloc(1024 * 4);
    double*       md0    = (double*)alloc(105 * 8 + 256 * 8);
    double*       s1d    = (double*)((char*)md0 + 105 * 8);
    double*       sq1d   = s1d + 128;
    float*        sc0    = (float*)alloc(64 * 4);
    float*        sh0    = (float*)alloc(64 * 4);
    float*        sc1    = (float*)alloc(128 * 4);
    float*        sh1    = (float*)alloc(128 * 4);
    if (off > ws_size) return;

    hipMemsetAsync(counts, 0, (size_t)CANVASv * 4 * 5, stream);
    hipMemsetAsync(md0, 0, 105 * 8 + 256 * 8, stream);

    int blocksN = (n + 255) / 256;
    k_scatter1<<<blocksN, 256, 0, stream>>>((const float4*)feat, (const int4*)coor, vidx, counts, sumc, n);
    k_scatter2<<<blocksN, 256, 0, stream>>>((const float4*)feat, vidx, counts, sumc, spd, n);
    k_prex<<<512, 256, 0, stream>>>((const float4*)feat, (const int4*)coor, vidx, counts, sumc, spd, x, n);
    k_mom<<<512, 256, 0, stream>>>((const uint4*)x, md0, n);
    k_fin0<<<1, 64, 0, stream>>>(md0, W0, g0, b0, sc0, sh0, n);

    // counting sort by voxel
    k_scanA<<<CANVASv / 1024, 1024, 0, stream>>>(counts, starts, bsum);
    k_scanB<<<1, 1024, 0, stream>>>(bsum, boff);
    k_scanC<<<CANVASv / 1024, 1024, 0, stream>>>(starts, boff);
    k_perm<<<blocksN, 256, 0, stream>>>(vidx, starts, perm, n);
    // per-voxel max + per-point p0 (starts is now inclusive prefix)
    k_vmaxv<<<(CANVASv + 3) / 4, 256, 0, stream>>>(x, W0, sc0, sh0, starts, perm, p0, vmaxb, CANVASv);

    int ntiles1 = (n + 127) / 128;
    hipFuncSetAttribute((const void*)k_gemm1s, hipFuncAttributeMaxDynamicSharedMemorySize, G1_LDS);
    k_gemm1s<<<512, 512, G1_LDS, stream>>>(p0, vmaxb, vidx, W1, y1, s1d, sq1d, n, ntiles1);

    k_fin1s<<<1, 128, 0, stream>>>(s1d, sq1d, g1, b1, sc1, sh1, n);

    int ntiles2 = (n + 63) / 64;
    hipFuncSetAttribute((const void*)k_fused2, hipFuncAttributeMaxDynamicSharedMemorySize, F2_LDS);
    k_fused2<<<512, 256, F2_LDS, stream>>>((const uint4*)y1, x, Wsp, bsp, sc1, sh1, outp, n, ntiles2);
}